// Round 19
// baseline (480.071 us; speedup 1.0000x reference)
//
#include <hip/hip_runtime.h>
#include <stdint.h>

typedef unsigned int uint;
typedef unsigned short u16;
typedef unsigned long long u64;

typedef float  f32x4 __attribute__((ext_vector_type(4)));
typedef uint   u32x4 __attribute__((ext_vector_type(4)));
typedef u16    u16x4 __attribute__((ext_vector_type(4)));
typedef u16    u16x8 __attribute__((ext_vector_type(8)));
typedef __bf16 bf16x8 __attribute__((ext_vector_type(8)));

#define DEV static __device__ __forceinline__
#define MFMA(a,b,c) __builtin_amdgcn_mfma_f32_16x16x32_bf16((a),(b),(c),0,0,0)
#define GLDS(src,dst) __builtin_amdgcn_global_load_lds((const __attribute__((address_space(1))) void*)(src),(__attribute__((address_space(3))) void*)(dst),16,0,0)

DEV u16 f2bf(float x){ union{float f;uint u;} v; v.f=x; return (u16)((v.u + 0x7fffu + ((v.u>>16)&1u))>>16); }
DEV float bf2f(u16 b){ union{uint u;float f;} v; v.u=((uint)b)<<16; return v.f; }
DEV int imin(int a,int b){ return a<b?a:b; }

// ---------------- fused converts ----------------
__global__ void cvt_all(
    const float* __restrict__ hs, const float* __restrict__ wqa, const float* __restrict__ iwqb,
    const float* __restrict__ iwk, const float* __restrict__ iwp,
    const float* __restrict__ wqbw, const float* __restrict__ wkva, const float* __restrict__ wkvb,
    const float* __restrict__ wow,
    u16* __restrict__ hid_hi, u16* __restrict__ hid_lo, u16* __restrict__ wqa_hi, u16* __restrict__ wqa_lo,
    u16* __restrict__ iwqb_hi, u16* __restrict__ iwqb_lo, u16* __restrict__ kiwp_hi, u16* __restrict__ kiwp_lo,
    u16* __restrict__ wqb_b, u16* __restrict__ wkva_b, u16* __restrict__ wkvb_b, u16* __restrict__ wo_b)
{
  int i = blockIdx.x*blockDim.x + threadIdx.x;
  int st = gridDim.x*blockDim.x;
  for(; i < 6537216; i += st){
    const float* src; u16 *dh, *dl=nullptr; int j; bool split;
    if(i < 1048576){ src=hs;   dh=hid_hi;  dl=hid_lo;  j=i;         split=true; }
    else if(i < 1835008){ src=wqa;  dh=wqa_hi;  dl=wqa_lo;  j=i-1048576; split=true; }
    else if(i < 3407872){ src=iwqb; dh=iwqb_hi; dl=iwqb_lo; j=i-1835008; split=true; }
    else if(i < 3473408){ src=iwk;  dh=kiwp_hi; dl=kiwp_lo; j=i-3407872; split=true; }
    else if(i < 3489792){ src=iwp;  dh=kiwp_hi+128*2048; dl=kiwp_lo+128*2048; j=i-3473408; split=true; }
    else if(i < 4669440){ src=wqbw; dh=wqb_b;  j=i-3489792; split=false; }
    else if(i < 4964352){ src=wkva; dh=wkva_b; j=i-4669440; split=false; }
    else if(i < 5488640){ src=wkvb; dh=wkvb_b; j=i-4964352; split=false; }
    else               { src=wow;  dh=wo_b;   j=i-5488640; split=false; }
    f32x4 x = reinterpret_cast<const f32x4*>(src)[j];
    u16x4 h;
    #pragma unroll
    for(int k=0;k<4;k++) h[k]=f2bf(x[k]);
    reinterpret_cast<u16x4*>(dh)[j]=h;
    if(split){
      u16x4 l;
      #pragma unroll
      for(int k=0;k<4;k++) l[k]=f2bf(x[k]-bf2f(h[k]));
      reinterpret_cast<u16x4*>(dl)[j]=l;
    }
  }
}

// ---------------- GEMM (glds staging + T2 XOR swizzle, m97 structure) ----------------
// EPI=0: plain f32 store (with split-K plane). EPI=1: fused q-rope + log2e/sqrt(192) scale + bf16 store.
template<int BK>
DEV void stageT(const u16* __restrict__ gbase, int ld, int row0, int maxrow, int k0, u16* lds){
  int tid = threadIdx.x, w = tid>>6, l = tid&63;
  if(BK==32){
    #pragma unroll
    for(int j=0;j<2;j++){
      int seg = w + j*4;
      int row = seg*16 + (l>>2);
      int gr = row0 + row; if(gr > maxrow) gr = maxrow;
      int u = (l&3) ^ ((l>>2)&3);
      GLDS(gbase + (size_t)gr*ld + k0 + u*8, lds + seg*512);
    }
  } else { // BK==64
    #pragma unroll
    for(int j=0;j<4;j++){
      int c = w + j*4;
      int row = c*8 + (l>>3);
      int gr = row0 + row; if(gr > maxrow) gr = maxrow;
      int u = (l&7) ^ ((l>>3)&7);
      GLDS(gbase + (size_t)gr*ld + k0 + u*8, lds + c*512);
    }
  }
}

template<int SPLIT, int BK, int EPI>
__global__ __launch_bounds__(256,2) void gemm_glds(
    const u16* __restrict__ Ah, const u16* __restrict__ Al, int lda,
    const u16* __restrict__ Bh, const u16* __restrict__ Bl, int ldb,
    float* __restrict__ C, int ldc, int M, int N, int K,
    u16* __restrict__ O1, const float* __restrict__ fcos, const float* __restrict__ fsin)
{
  __shared__ u16 sAh[128*BK];
  __shared__ u16 sBh[128*BK];
  __shared__ u16 sAl[SPLIT?128*BK:8];
  __shared__ u16 sBl[SPLIT?128*BK:8];
  const int tid = threadIdx.x;
  const int w = tid>>6, l = tid&63;
  const int wr = w>>1, wc = w&1;
  const int l15 = l&15, l16 = l>>4;
  const int UM = BK/8 - 1;

  int gx = gridDim.x;
  int nwg = gx*gridDim.y;
  int orig = blockIdx.x + gx*blockIdx.y;
  int qq = nwg>>3, rr = nwg&7, xc = orig&7, oo = orig>>3;
  int wg = (xc<rr ? xc*(qq+1) : rr*(qq+1)+(xc-rr)*qq) + oo;
  int m0 = (wg/gx)*128, n0 = (wg%gx)*128;

  int kz = K/(int)gridDim.z;
  int kbeg = blockIdx.z*kz;

  f32x4 acc[4][4];
  #pragma unroll
  for(int m=0;m<4;m++)
    #pragma unroll
    for(int n=0;n<4;n++) acc[m][n] = f32x4{0.f,0.f,0.f,0.f};

  for(int k0=kbeg; k0<kbeg+kz; k0+=BK){
    __syncthreads();
    stageT<BK>(Ah, lda, m0, M-1, k0, sAh);
    stageT<BK>(Bh, ldb, n0, N-1, k0, sBh);
    if(SPLIT){
      stageT<BK>(Al, lda, m0, M-1, k0, sAl);
      stageT<BK>(Bl, ldb, n0, N-1, k0, sBl);
    }
    asm volatile("s_waitcnt vmcnt(0)" ::: "memory");
    __syncthreads();
    #pragma unroll
    for(int kk=0;kk<BK/32;kk++){
      bf16x8 ah[4], bh[4];
      #pragma unroll
      for(int m=0;m<4;m++){
        int row = wr*64+m*16+l15;
        ah[m] = *reinterpret_cast<const bf16x8*>(&sAh[row*BK + ((kk*4+l16)^(row&UM))*8]);
      }
      #pragma unroll
      for(int n=0;n<4;n++){
        int row = wc*64+n*16+l15;
        bh[n] = *reinterpret_cast<const bf16x8*>(&sBh[row*BK + ((kk*4+l16)^(row&UM))*8]);
      }
      #pragma unroll
      for(int m=0;m<4;m++)
        #pragma unroll
        for(int n=0;n<4;n++) acc[m][n] = MFMA(ah[m], bh[n], acc[m][n]);
      if(SPLIT){
        bf16x8 t[4];
        #pragma unroll
        for(int n=0;n<4;n++){
          int row = wc*64+n*16+l15;
          t[n] = *reinterpret_cast<const bf16x8*>(&sBl[row*BK + ((kk*4+l16)^(row&UM))*8]);
        }
        #pragma unroll
        for(int m=0;m<4;m++)
          #pragma unroll
          for(int n=0;n<4;n++) acc[m][n] = MFMA(ah[m], t[n], acc[m][n]);
        #pragma unroll
        for(int m=0;m<4;m++){
          int row = wr*64+m*16+l15;
          t[m] = *reinterpret_cast<const bf16x8*>(&sAl[row*BK + ((kk*4+l16)^(row&UM))*8]);
        }
        #pragma unroll
        for(int m=0;m<4;m++)
          #pragma unroll
          for(int n=0;n<4;n++) acc[m][n] = MFMA(t[m], bh[n], acc[m][n]);
      }
    }
  }
  if(EPI==0){
    float* Cp = C + (size_t)blockIdx.z*M*ldc;
    #pragma unroll
    for(int m=0;m<4;m++){
      int row = m0 + wr*64 + m*16 + l16*4;
      #pragma unroll
      for(int n=0;n<4;n++){
        int col = n0 + wc*64 + n*16 + l15;
        if(col < N){
          #pragma unroll
          for(int r=0;r<4;r++){
            int rrow = row + r;
            if(rrow < M) Cp[(size_t)rrow*ldc + col] = acc[m][n][r];
          }
        }
      }
    }
  } else {
    // EPI==1: fused q-rope (interleaved pairs = xor-adjacent lanes) + scale + bf16
    const float qsc = 0.10411756f;   // log2(e)/sqrt(192)
    #pragma unroll
    for(int m=0;m<4;m++){
      int rowb = m0 + wr*64 + m*16 + l16*4;
      #pragma unroll
      for(int n=0;n<4;n++){
        int col = n0 + wc*64 + n*16 + l15;
        int hq = col/192;
        int d  = col - hq*192;
        #pragma unroll
        for(int r=0;r<4;r++){
          int row = rowb + r;
          float v = acc[m][n][r];
          float p = __shfl_xor(v, 1, 64);   // pair partner (co-active: d parity == lane parity)
          float vv;
          if(d < 128) vv = v;
          else{
            int i2 = (d-128)>>1;
            float c0 = fcos[row*32 + i2], s_ = fsin[row*32 + i2];
            vv = ((d&1)==0) ? (v*c0 - p*s_) : (p*s_ + v*c0);
          }
          O1[(size_t)row*3072 + col] = f2bf(vv*qsc);
        }
      }
    }
  }
}

// ---------------- norms / rope ----------------
__global__ __launch_bounds__(256) void rmsnorm_qr_split(
    const float* __restrict__ in, const float* __restrict__ w,
    u16* __restrict__ hi, u16* __restrict__ lo)
{
  int s = blockIdx.x, tid = threadIdx.x;
  __shared__ float red[4];
  const float* x = in + (size_t)s*1536;
  const size_t plane = 2048ull*1536;
  float xv[6]; float ss=0.f;
  #pragma unroll
  for(int i=0;i<6;i++){ int c = tid+i*256; xv[i] = x[c] + x[plane+c]; ss += xv[i]*xv[i]; }
  #pragma unroll
  for(int o=32;o>0;o>>=1) ss += __shfl_down(ss,o,64);
  if((tid&63)==0) red[tid>>6]=ss;
  __syncthreads();
  float total = red[0]+red[1]+red[2]+red[3];
  float scale = rsqrtf(total*(1.0f/1536.0f) + 1e-6f);
  #pragma unroll
  for(int i=0;i<6;i++){
    int c = tid + i*256;
    float vv = xv[i]*scale*w[c];
    u16 hv = f2bf(vv);
    hi[(size_t)s*1536+c]=hv;
    lo[(size_t)s*1536+c]=f2bf(vv - bf2f(hv));
  }
}

__global__ __launch_bounds__(256) void kv_norm_rope(
    const float* __restrict__ kva, const float* __restrict__ w,
    const float* __restrict__ fcos, const float* __restrict__ fsin,
    u16* __restrict__ kvb, float* __restrict__ kpe)
{
  int s = blockIdx.x, tid = threadIdx.x;
  __shared__ float red[4];
  const size_t plane = 2048ull*576;
  float xv[2]={0.f,0.f};
  #pragma unroll
  for(int c=0;c<4;c++){
    const float* xp = kva + (size_t)c*plane + (size_t)s*576;
    xv[0]+=xp[tid]; xv[1]+=xp[tid+256];
  }
  float ss = xv[0]*xv[0]+xv[1]*xv[1];
  #pragma unroll
  for(int o=32;o>0;o>>=1) ss += __shfl_down(ss,o,64);
  if((tid&63)==0) red[tid>>6]=ss;
  __syncthreads();
  float total = red[0]+red[1]+red[2]+red[3];
  float scale = rsqrtf(total*(1.0f/512.0f)+1e-6f);
  #pragma unroll
  for(int i=0;i<2;i++){ int c=tid+i*256; kvb[(size_t)s*512+c]=f2bf(xv[i]*scale*w[c]); }
  if(tid<32){
    float x0=0.f, x1=0.f;
    #pragma unroll
    for(int c=0;c<4;c++){
      const float* xp = kva + (size_t)c*plane + (size_t)s*576;
      x0 += xp[512+2*tid]; x1 += xp[513+2*tid];
    }
    float c0=fcos[(size_t)s*32+tid], s_=fsin[(size_t)s*32+tid];
    kpe[(size_t)s*64+2*tid]   = x0*c0 - x1*s_;
    kpe[(size_t)s*64+2*tid+1] = x0*s_ + x1*c0;
  }
}

__global__ __launch_bounds__(256) void qi_rope_split(const float* __restrict__ qpre,
    const float* __restrict__ fcos, const float* __restrict__ fsin,
    u16* __restrict__ hi, u16* __restrict__ lo)
{
  int s = blockIdx.x;
  const float* rowp = qpre + (size_t)s*4096;
  for(int idx=threadIdx.x; idx<4096; idx+=256){
    int hh = idx>>7, d = idx&127;
    const float* hb = rowp + (hh<<7);
    float vv;
    if(d<32){ float c0=fcos[(size_t)s*32+d], s_=fsin[(size_t)s*32+d]; vv = hb[d]*c0 - hb[d+32]*s_; }
    else if(d<64){ int i2=d-32; float c0=fcos[(size_t)s*32+i2], s_=fsin[(size_t)s*32+i2]; vv = hb[i2]*s_ + hb[d]*c0; }
    else vv = hb[d];
    u16 hv = f2bf(vv);
    hi[(size_t)s*4096+idx]=hv;
    lo[(size_t)s*4096+idx]=f2bf(vv - bf2f(hv));
  }
}

__global__ __launch_bounds__(128) void ki_ln_rope_split(
    const float* __restrict__ kpre, const float* __restrict__ w, const float* __restrict__ bb,
    const float* __restrict__ fcos, const float* __restrict__ fsin,
    u16* __restrict__ hi, u16* __restrict__ lo, float* __restrict__ wts_out)
{
  int s = blockIdx.x, tid = threadIdx.x;
  __shared__ float red[2];
  __shared__ float ybuf[128];
  const size_t plane = 2048ull*160;
  float x = 0.f;
  #pragma unroll
  for(int c=0;c<8;c++) x += kpre[(size_t)c*plane + (size_t)s*160 + tid];
  if(tid<32){
    float ws = 0.f;
    #pragma unroll
    for(int c=0;c<8;c++) ws += kpre[(size_t)c*plane + (size_t)s*160 + 128 + tid];
    wts_out[(size_t)s*160 + 128 + tid] = ws;
  }
  float v = x;
  #pragma unroll
  for(int o=32;o>0;o>>=1) v += __shfl_down(v,o,64);
  if((tid&63)==0) red[tid>>6]=v;
  __syncthreads();
  float mean = (red[0]+red[1])*(1.f/128.f);
  __syncthreads();
  float dx = x - mean;
  v = dx*dx;
  #pragma unroll
  for(int o=32;o>0;o>>=1) v += __shfl_down(v,o,64);
  if((tid&63)==0) red[tid>>6]=v;
  __syncthreads();
  float var = (red[0]+red[1])*(1.f/128.f);
  float y = dx*rsqrtf(var+1e-5f)*w[tid] + bb[tid];
  ybuf[tid]=y;
  __syncthreads();
  float r;
  if(tid<32){ float c0=fcos[(size_t)s*32+tid], s_=fsin[(size_t)s*32+tid]; r = ybuf[tid]*c0 - ybuf[tid+32]*s_; }
  else if(tid<64){ int i2=tid-32; float c0=fcos[(size_t)s*32+i2], s_=fsin[(size_t)s*32+i2]; r = ybuf[i2]*s_ + ybuf[tid]*c0; }
  else r = y;
  u16 hv=f2bf(r);
  hi[(size_t)s*128+tid]=hv;
  lo[(size_t)s*128+tid]=f2bf(r-bf2f(hv));
}

// transpose V + assemble K in one kernel. grid (32, 16)
__global__ __launch_bounds__(256) void transpose_assemble(const float* __restrict__ kvp,
    const float* __restrict__ kpe, u16* __restrict__ vt, u16* __restrict__ kb){
  __shared__ u16 T[64*136];
  int s0 = blockIdx.x*64, h = blockIdx.y;
  int tid = threadIdx.x;
  for(int idx=tid; idx<64*192; idx+=256){
    int r = idx/192, d = idx - r*192;
    float val = (d<128) ? kvp[(size_t)(s0+r)*4096 + h*256 + d] : kpe[(size_t)(s0+r)*64 + (d-128)];
    kb[((size_t)(s0+r)*16 + h)*192 + d] = f2bf(val);
  }
  #pragma unroll
  for(int i=0;i<8;i++){
    int ch = i*256 + tid;
    int r = ch>>5, cc = ch&31;
    f32x4 x = *reinterpret_cast<const f32x4*>(&kvp[(size_t)(s0+r)*4096 + h*256 + 128 + cc*4]);
    u16x4 y;
    #pragma unroll
    for(int j=0;j<4;j++) y[j] = f2bf(x[j]);
    *reinterpret_cast<u16x4*>(&T[r*136 + cc*4]) = y;
  }
  __syncthreads();
  #pragma unroll
  for(int i=0;i<4;i++){
    int ch = i*256 + tid;
    int d = ch>>3, sc = ch&7;
    u16x8 y;
    #pragma unroll
    for(int j=0;j<8;j++) y[j] = T[(sc*8+j)*136 + d];
    *reinterpret_cast<u16x8*>(&vt[((size_t)h*128 + d)*2048 + s0 + sc*8]) = y;
  }
}

// ---------------- fused indexer scores v8 (best: 82us) ----------------
DEV void isc_pass64(const u16* __restrict__ Q, const u16* __restrict__ Kb,
                    f32x4 (&sc)[2][2], int wm, int wn, int l15, int l16){
  #pragma unroll
  for(int ks=0;ks<4;ks++){
    bf16x8 a[2], b[2];
    #pragma unroll
    for(int m=0;m<2;m++){
      int row = wm*32 + m*16 + l15;
      a[m] = *reinterpret_cast<const bf16x8*>(&Q[row*128 + ((((ks<<2)+l16) ^ (row&7))<<3)]);
    }
    #pragma unroll
    for(int n=0;n<2;n++){
      int row = wn*32 + n*16 + l15;
      b[n] = *reinterpret_cast<const bf16x8*>(&Kb[row*128 + ((((ks<<2)+l16) ^ (row&7))<<3)]);
    }
    #pragma unroll
    for(int m=0;m<2;m++)
      #pragma unroll
      for(int n=0;n<2;n++) sc[m][n] = MFMA(a[m], b[n], sc[m][n]);
  }
}

__global__ __launch_bounds__(512,4) void idx_scores7(
    const u16* __restrict__ qih, const u16* __restrict__ qil,
    const u16* __restrict__ kih, const u16* __restrict__ kil,
    const float* __restrict__ wts,
    float* __restrict__ p0, float* __restrict__ p1, float* __restrict__ p2, float* __restrict__ p3)
{
  __shared__ u16 Kh[128*128];
  __shared__ u16 Kl[128*128];
  __shared__ u16 Qb[64*128];
  int orig = blockIdx.x;
  int bid = (orig&7)*136 + (orig>>3);
  int tileIdx = bid>>2, hg = bid&3;
  int si=0, t=tileIdx;
  #pragma unroll 1
  for(; si<32; si++){ int cnt=(si+2)>>1; if(t<cnt) break; t-=cnt; }
  int s0 = si*64, t0 = t*128;
  float* plane = (hg==0)?p0:(hg==1)?p1:(hg==2)?p2:p3;
  float* outp = plane + (size_t)tileIdx*8192;
  int h0 = hg*8;
  int tid=threadIdx.x, w=tid>>6, l=tid&63;
  int wm=w>>2, wn=w&3, l15=l&15, l16=l>>4;
  const float cscale = 0.015625f;
  #pragma unroll
  for(int rnd=0;rnd<4;rnd++){
    int cid = rnd*512 + w*64 + l;
    int row = cid>>4, cc = cid&15;
    int scc = cc ^ (row&7);
    GLDS(kih + (size_t)(t0+row)*128 + scc*8, Kh + rnd*4096 + w*512);
    GLDS(kil + (size_t)(t0+row)*128 + scc*8, Kl + rnd*4096 + w*512);
  }
  #pragma unroll
  for(int rnd=0;rnd<2;rnd++){
    int cid = rnd*512 + w*64 + l;
    int row = cid>>4, cc = cid&15;
    int scc = cc ^ (row&7);
    GLDS(qih + (size_t)(s0+row)*4096 + h0*128 + scc*8, Qb + rnd*4096 + w*512);
  }
  asm volatile("s_waitcnt vmcnt(0)" ::: "memory");
  __syncthreads();
  f32x4 accI[2][2], sc[2][2];
  #pragma unroll
  for(int m=0;m<2;m++) for(int n=0;n<2;n++) accI[m][n] = f32x4{0.f,0.f,0.f,0.f};
  for(int s=0;s<16;s++){
    const u16* Q = Qb;
    if((s&1)==0){
      #pragma unroll
      for(int m=0;m<2;m++) for(int n=0;n<2;n++) sc[m][n] = f32x4{0.f,0.f,0.f,0.f};
      isc_pass64(Q, Kh, sc, wm, wn, l15, l16);
      isc_pass64(Q, Kl, sc, wm, wn, l15, l16);
    } else {
      isc_pass64(Q, Kh, sc, wm, wn, l15, l16);
      int hh = h0 + (s>>1);
      #pragma unroll
      for(int m=0;m<2;m++)
        #pragma unroll
        for(int r=0;r<4;r++){
          float wv = wts[(size_t)(s0+wm*32+m*16+l16*4+r)*160 + 128 + hh]*cscale;
          #pragma unroll
          for(int n=0;n<2;n++) accI[m][n][r] += fmaxf(sc[m][n][r],0.f)*wv;
        }
    }
    __syncthreads();
    int nxt = s+1;
    if(nxt < 16){
      const u16* src = (nxt&1) ? qil : qih;
      int hh = h0 + (nxt>>1);
      #pragma unroll
      for(int rnd=0;rnd<2;rnd++){
        int cid = rnd*512 + w*64 + l;
        int row = cid>>4, cc = cid&15;
        int scc = cc ^ (row&7);
        GLDS(src + (size_t)(s0+row)*4096 + hh*128 + scc*8, Qb + rnd*4096 + w*512);
      }
      asm volatile("s_waitcnt vmcnt(0)" ::: "memory");
      __syncthreads();
    }
  }
  #pragma unroll
  for(int m=0;m<2;m++)
    #pragma unroll
    for(int n=0;n<2;n++)
      #pragma unroll
      for(int r=0;r<4;r++)
        outp[(wm*32+m*16+l16*4+r)*128 + wn*32 + n*16 + l15] = accI[m][n][r];
}

// ---------------- exact top-512 per row -> bitmask ----------------
DEV uint fkey(float f){ union{float f;uint u;} v; v.f=f; return (v.u & 0x80000000u) ? ~v.u : (v.u | 0x80000000u); }

__global__ __launch_bounds__(256) void topk_mask(
    const float* __restrict__ p0, const float* __restrict__ p1,
    const float* __restrict__ p2, const float* __restrict__ p3, u64* __restrict__ bits)
{
  int s = blockIdx.x;
  int n = s+1;
  int tid = threadIdx.x;
  if(n <= 512){
    for(int wI=tid; wI<32; wI+=256){
      u64 m=0; int base=wI*64;
      if(base < n){ int cnt=n-base; m = (cnt>=64)? ~0ull : ((1ull<<cnt)-1ull); }
      bits[(size_t)s*32+wI]=m;
    }
    return;
  }
  __shared__ float row[2048];
  __shared__ uint hist[256];
  __shared__ uint sh_B, sh_k;
  __shared__ uint wcnt[32];
  int si = s>>6, sr = s&63;
  size_t triBase = (size_t)(((si+1)*(si+1))>>2);
  for(int c=tid; c<n; c+=256){
    size_t off = (triBase + (size_t)(c>>7))*8192 + (size_t)sr*128 + (c&127);
    row[c] = p0[off]+p1[off]+p2[off]+p3[off];
  }
  __syncthreads();
  uint prefix=0, k=512;
  for(int shift=24; shift>=0; shift-=8){
    hist[tid]=0;
    __syncthreads();
    for(int t2=tid;t2<n;t2+=256){
      uint u = fkey(row[t2]);
      bool ok = (shift==24) || ((u>>(shift+8)) == (prefix>>(shift+8)));
      if(ok) atomicAdd(&hist[(u>>shift)&255u],1u);
    }
    __syncthreads();
    for(int offd=1; offd<256; offd<<=1){
      uint add = (tid+offd<256)? hist[tid+offd] : 0u;
      __syncthreads();
      hist[tid] += add;
      __syncthreads();
    }
    uint nxtv = (tid<255)? hist[tid+1] : 0u;
    if(hist[tid]>=k && nxtv<k){ sh_B=(uint)tid; sh_k = k - nxtv; }
    __syncthreads();
    prefix |= sh_B<<shift;
    k = sh_k;
    __syncthreads();
  }
  uint thr = prefix;
  if(tid<32) wcnt[tid]=0;
  __syncthreads();
  int nw = (n+63)>>6;
  if(tid < nw){
    int base=tid*64, end = base+64; if(end>n) end=n;
    uint c=0;
    for(int t2=base;t2<end;t2++) if(fkey(row[t2])==thr) c++;
    wcnt[tid]=c;
  }
  __syncthreads();
  if(tid==0){
    uint runv=0;
    for(int i=0;i<32;i++){ uint c=wcnt[i]; wcnt[i]=runv; runv+=c; }
  }
  __syncthreads();
  if(tid<32){
    u64 m=0; int base=tid*64;
    if(base<n){
      uint rank = wcnt[tid];
      int end = base+64; if(end>n) end=n;
      for(int t2=base;t2<end;t2++){
        uint u = fkey(row[t2]);
        if(u>thr) m |= (1ull<<(t2-base));
        else if(u==thr){ if(rank<k) m |= (1ull<<(t2-base)); rank++; }
      }
    }
    bits[(size_t)s*32+tid]=m;
  }
}

// ---------------- flash attention: no-max exp2 softmax, 3 blocks/CU ----------------
__global__ __launch_bounds__(256,3) void flash_attn(
    const u16* __restrict__ q, const u16* __restrict__ k, const u16* __restrict__ vt,
    const u64* __restrict__ bits, u16* __restrict__ o,
    u16* __restrict__ Opart, float* __restrict__ ml)
{
  __shared__ u16 Ks[64*192];
  __shared__ u16 Vt[128*64];
  __shared__ u16 Pl[64*72];
  int h = blockIdx.y;
  int pp = blockIdx.x;
  int sblk=0, chunk=0;
  for(int i=0;i<32;i++){
    int sb = 31-i; int ncc = (sb>>3)+1;
    if(pp < ncc){ sblk=sb; chunk=pp; break; }
    pp -= ncc;
  }
  int nc = (sblk>>3)+1, ntiles = sblk+1, s0 = sblk*64;
  int tid=threadIdx.x, w=tid>>6, l=tid&63;
  int l15=l&15, l16=l>>4;
  bf16x8 qf[6];
  #pragma unroll
  for(int ks=0;ks<6;ks++)
    qf[ks] = *reinterpret_cast<const bf16x8*>(&q[((size_t)(s0+w*16+l15)*16 + h)*192 + ks*32 + l16*8]);
  f32x4 Oa[8];
  #pragma unroll
  for(int n=0;n<8;n++) Oa[n] = f32x4{0.f,0.f,0.f,0.f};
  float lrun[4];
  #pragma unroll
  for(int r=0;r<4;r++) lrun[r]=0.f;
  int tt0 = chunk*8, tt1 = imin(tt0+8, ntiles);
  for(int tt=tt0; tt<tt1; tt++){
    int t0 = tt*64;
    __syncthreads();
    #pragma unroll
    for(int rnd=0;rnd<6;rnd++){
      int cid = rnd*256 + w*64 + l;
      int row = cid/24, cc = cid - row*24;
      int scc = cc ^ (row&7);
      GLDS(k + ((size_t)(t0+row)*16 + h)*192 + scc*8, Ks + rnd*2048 + w*512);
    }
    #pragma unroll
    for(int rnd=0;rnd<4;rnd++){
      int cid = rnd*256 + w*64 + l;
      int row = cid>>3, cc = cid&7;
      int scc = cc ^ (row&7);
      GLDS(vt + ((size_t)h*128 + row)*2048 + t0 + scc*8, Vt + rnd*2048 + w*512);
    }
    asm volatile("s_waitcnt vmcnt(0)" ::: "memory");
    __syncthreads();
    f32x4 S[4];
    #pragma unroll
    for(int n=0;n<4;n++) S[n] = f32x4{0.f,0.f,0.f,0.f};
    #pragma unroll
    for(int ks=0;ks<6;ks++){
      bf16x8 b[4];
      #pragma unroll
      for(int n=0;n<4;n++){
        int row = n*16+l15;
        b[n] = *reinterpret_cast<const bf16x8*>(&Ks[row*192 + ((((ks<<2)+l16) ^ (row&7))<<3)]);
      }
      #pragma unroll
      for(int n=0;n<4;n++) S[n] = MFMA(qf[ks], b[n], S[n]);
    }
    bool diag = (tt == sblk);
    #pragma unroll
    for(int r=0;r<4;r++){
      int srow = s0 + w*16 + l16*4 + r;
      u64 wrd = bits[(size_t)srow*32 + (t0>>6)];
      if(diag) wrd &= (((1ull<<(srow&63))<<1) - 1ull);
      float rs = 0.f;
      #pragma unroll
      for(int n=0;n<4;n++){
        int bitp = n*16 + l15;
        bool ok = (wrd>>bitp)&1ull;
        float p = ok ? exp2f(S[n][r]) : 0.f;
        S[n][r] = p;
        rs += p;
      }
      #pragma unroll
      for(int off=1;off<16;off<<=1) rs += __shfl_xor(rs, off, 64);
      lrun[r] += rs;
    }
    #pragma unroll
    for(int n=0;n<4;n++)
      #pragma unroll
      for(int r=0;r<4;r++)
        Pl[(w*16+l16*4+r)*72 + n*16+l15] = f2bf(S[n][r]);
    #pragma unroll
    for(int ks=0;ks<2;ks++){
      bf16x8 a = *reinterpret_cast<const bf16x8*>(&Pl[(w*16+l15)*72 + ks*32 + l16*8]);
      bf16x8 bb[8];
      #pragma unroll
      for(int n=0;n<8;n++){
        int d = n*16+l15;
        bb[n] = *reinterpret_cast<const bf16x8*>(&Vt[d*64 + ((((ks<<2)+l16) ^ (d&7))<<3)]);
      }
      #pragma unroll
      for(int n=0;n<8;n++) Oa[n] = MFMA(a, bb[n], Oa[n]);
    }
  }
  if(nc == 1){
    #pragma unroll
    for(int r=0;r<4;r++){
      int srow = s0 + w*16 + l16*4 + r;
      float inv = 1.f/lrun[r];
      #pragma unroll
      for(int n=0;n<8;n++)
        o[(size_t)srow*2048 + h*128 + n*16 + l15] = f2bf(Oa[n][r]*inv);
    }
  } else {
    int part = ((h*32 + sblk)<<2) + chunk;
    u16* Op = Opart + (size_t)part*8192;
    #pragma unroll
    for(int r=0;r<4;r++){
      int rit = w*16 + l16*4 + r;
      #pragma unroll
      for(int n=0;n<8;n++)
        Op[rit*128 + n*16 + l15] = f2bf(Oa[n][r]);
      if(l15==0)
        ml[(size_t)part*128 + rit*2+1] = lrun[r];
    }
  }
}

__global__ __launch_bounds__(256) void flash_combine(
    const u16* __restrict__ Opart, const float* __restrict__ ml, u16* __restrict__ o)
{
  int b = blockIdx.x;
  int h = b/24, sblk = 8 + (b%24);
  int nc = (sblk>>3)+1;
  int tid = threadIdx.x;
  int r = tid>>2, dq = (tid&3)*32;
  int s0 = sblk*64;
  int pbase = (h*32+sblk)<<2;
  float L = 0.f;
  for(int c=0;c<nc;c++) L += ml[(size_t)(pbase+c)*128 + r*2 + 1];
  float inv = 1.f/L;
  for(int dd=0; dd<32; dd+=8){
    float accv[8];
    #pragma unroll
    for(int j=0;j<8;j++) accv[j]=0.f;
    for(int c=0;c<nc;c++){
      u16x8 pv = *reinterpret_cast<const u16x8*>(&Opart[(size_t)(pbase+c)*8192 + r*128 + dq + dd]);
      #pragma unroll
      for(int j=0;j<8;j++) accv[j] += bf2f(pv[j]);
    }
    u16x8 ov;
    #pragma unroll
    for(int j=0;j<8;j++) ov[j] = f2bf(accv[j]*inv);
    *reinterpret_cast<u16x8*>(&o[(size_t)(s0+r)*2048 + h*128 + dq + dd]) = ov;
  }
}

// ---------------- host ----------------
extern "C" void kernel_launch(void* const* d_in, const int* in_sizes, int n_in,
                              void* d_out, int out_size, void* d_ws, size_t ws_size,
                              hipStream_t stream)
{
  (void)in_sizes; (void)n_in; (void)out_size;
  const float* hs   = (const float*)d_in[0];
  const float* wqa  = (const float*)d_in[1];
  const float* qnw  = (const float*)d_in[2];
  const float* wqbw = (const float*)d_in[3];
  const float* wkva = (const float*)d_in[4];
  const float* kvnw = (const float*)d_in[5];
  const float* wkvb = (const float*)d_in[6];
  const float* wow  = (const float*)d_in[7];
  const float* iwqb = (const float*)d_in[8];
  const float* iwk  = (const float*)d_in[9];
  const float* iknw = (const float*)d_in[10];
  const float* iknb = (const float*)d_in[11];
  const float* iwp  = (const float*)d_in[12];
  const float* fcos = (const float*)d_in[13];
  const float* fsin = (const float*)d_in[14];
  float* outp = (float*)d_out;

  char* base = (char*)d_ws;
  size_t off = 0;
  auto alloc = [&](size_t bytes)->char*{ char* p = base+off; off += (bytes+255)&~(size_t)255; return p; };
  u16* hid_hi = (u16*)alloc(2048ull*2048*2);
  u16* hid_lo = (u16*)alloc(2048ull*2048*2);
  u16* wqa_hi = (u16*)alloc(1536ull*2048*2);
  u16* wqa_lo = (u16*)alloc(1536ull*2048*2);
  u16* wqb_b  = (u16*)alloc(3072ull*1536*2);
  u16* wkva_b = (u16*)alloc(576ull*2048*2);
  u16* wkvb_b = (u16*)alloc(4096ull*512*2);
  u16* wo_b   = (u16*)alloc(2048ull*2048*2);
  u16* iwqb_hi= (u16*)alloc(4096ull*1536*2);
  u16* iwqb_lo= (u16*)alloc(4096ull*1536*2);
  u16* kiwp_hi= (u16*)alloc(160ull*2048*2);
  u16* kiwp_lo= (u16*)alloc(160ull*2048*2);
  float* kiwp_C=(float*)alloc(2048ull*160*4);
  u16* qr_hi  = (u16*)alloc(2048ull*1536*2);
  u16* qr_lo  = (u16*)alloc(2048ull*1536*2);
  u16* kv_b   = (u16*)alloc(2048ull*512*2);
  float* kpe  = (float*)alloc(2048ull*64*4);
  u16* k_b    = (u16*)alloc(2048ull*16*192*2);
  u16* v_t    = (u16*)alloc(16ull*128*2048*2);
  u16* ki_hi  = (u16*)alloc(2048ull*128*2);
  u16* ki_lo  = (u16*)alloc(2048ull*128*2);
  u64* bits   = (u64*)alloc(2048ull*32*8);
  u16* attn_b = (u16*)alloc(2048ull*2048*2);
  float* reg1 = (float*)alloc(2048ull*4096*4);
  if(ws_size < off) return;

  // aliases (lifetime-checked)
  u16* q_b      = wqa_hi;            // spans wqa_hi+wqa_lo; wq_a dead after qr gemm; written by q-GEMM EPI=1
  u16* qi_hi    = hid_hi;            // spans hid_hi+hid_lo; hidden dead after kiwp gemm
  u16* qi_lo    = iwqb_hi;           // spans into iwqb_lo; idx_wq_b dead after qi gemm
  float* ml     = (float*)qr_lo;     // qr dead after qi gemm
  float* qr_pre = reg1;
  float* kva_part = reg1;
  float* kvp    = reg1;
  float* kiwp_part = reg1;
  float* qi_pre = reg1;
  const size_t PLANE = 272ull*8192;
  float* ip0 = reg1;
  float* ip1 = reg1 + PLANE;
  float* ip2 = reg1 + 2*PLANE;
  float* ip3 = (float*)wqb_b;        // wqb_b dead after q gemm
  u16* Opart = (u16*)reg1;

  auto G1 = [&](const u16* A,int lda,const u16* B,int ldb,float* C,int ldc,int M,int N,int K,int z){
    dim3 g((unsigned)((N+127)/128), (unsigned)((M+127)/128), (unsigned)z);
    gemm_glds<0,64,0><<<g,256,0,stream>>>(A,nullptr,lda,B,nullptr,ldb,C,ldc,M,N,K,nullptr,nullptr,nullptr);
  };
  auto G3 = [&](const u16* Ah,const u16* Al,int lda,const u16* Bh,const u16* Bl,int ldb,float* C,int ldc,int M,int N,int K,int z){
    dim3 g((unsigned)((N+127)/128), (unsigned)((M+127)/128), (unsigned)z);
    gemm_glds<1,64,0><<<g,256,0,stream>>>(Ah,Al,lda,Bh,Bl,ldb,C,ldc,M,N,K,nullptr,nullptr,nullptr);
  };

  cvt_all<<<2048,256,0,stream>>>(hs,wqa,iwqb,iwk,iwp,wqbw,wkva,wkvb,wow,
      hid_hi,hid_lo,wqa_hi,wqa_lo,iwqb_hi,iwqb_lo,kiwp_hi,kiwp_lo,
      wqb_b,wkva_b,wkvb_b,wo_b);

  // qr = rmsnorm(hidden @ wq_a^T), split-K z=2, plane-sum fused into rmsnorm
  G3(hid_hi,hid_lo,2048, wqa_hi,wqa_lo,2048, qr_pre,1536, 2048,1536,2048, 2);
  rmsnorm_qr_split<<<2048,256,0,stream>>>(qr_pre, qnw, qr_hi, qr_lo);

  // q path: GEMM with fused rope+scale+bf16 epilogue (writes q_b directly)
  {
    dim3 g(24, 16, 1);
    gemm_glds<0,64,1><<<g,256,0,stream>>>(qr_hi,nullptr,1536, wqb_b,nullptr,1536,
        nullptr,0, 2048,3072,1536, q_b, fcos, fsin);
  }

  // kv path (split-K z=4, plane-sum fused into kv_norm_rope)
  G1(hid_hi,2048, wkva_b,2048, kva_part,576, 2048,576,2048, 4);
  kv_norm_rope<<<2048,256,0,stream>>>(kva_part, kvnw, fcos, fsin, kv_b, kpe);
  G1(kv_b,512, wkvb_b,512, kvp,4096, 2048,4096,512, 1);
  transpose_assemble<<<dim3(32,16),256,0,stream>>>(kvp, kpe, v_t, k_b);

  // indexer ki + wts packed (N=160, split-K z=8)
  G3(hid_hi,hid_lo,2048, kiwp_hi,kiwp_lo,2048, kiwp_part,160, 2048,160,2048, 8);
  ki_ln_rope_split<<<2048,128,0,stream>>>(kiwp_part, iknw, iknb, fcos, fsin, ki_hi, ki_lo, kiwp_C);

  // indexer qi
  G3(qr_hi,qr_lo,1536, iwqb_hi,iwqb_lo,1536, qi_pre,4096, 2048,4096,1536, 1);
  qi_rope_split<<<2048,256,0,stream>>>(qi_pre, fcos, fsin, qi_hi, qi_lo);

  // fused index scores + topk
  idx_scores7<<<1088,512,0,stream>>>(qi_hi, qi_lo, ki_hi, ki_lo, kiwp_C, ip0, ip1, ip2, ip3);
  topk_mask<<<2048,256,0,stream>>>(ip0, ip1, ip2, ip3, bits);

  // attention + combine + output projection
  flash_attn<<<dim3(80,16),256,0,stream>>>(q_b, k_b, v_t, bits, attn_b, Opart, ml);
  flash_combine<<<384,256,0,stream>>>(Opart, ml, attn_b);
  G1(attn_b,2048, wo_b,2048, outp,2048, 2048,2048,2048, 1);
}

// Round 20
// 479.734 us; speedup vs baseline: 1.0007x; 1.0007x over previous
//
#include <hip/hip_runtime.h>
#include <stdint.h>

typedef unsigned int uint;
typedef unsigned short u16;
typedef unsigned long long u64;

typedef float  f32x4 __attribute__((ext_vector_type(4)));
typedef uint   u32x4 __attribute__((ext_vector_type(4)));
typedef u16    u16x4 __attribute__((ext_vector_type(4)));
typedef u16    u16x8 __attribute__((ext_vector_type(8)));
typedef __bf16 bf16x8 __attribute__((ext_vector_type(8)));

#define DEV static __device__ __forceinline__
#define MFMA(a,b,c) __builtin_amdgcn_mfma_f32_16x16x32_bf16((a),(b),(c),0,0,0)
#define GLDS(src,dst) __builtin_amdgcn_global_load_lds((const __attribute__((address_space(1))) void*)(src),(__attribute__((address_space(3))) void*)(dst),16,0,0)

DEV u16 f2bf(float x){ union{float f;uint u;} v; v.f=x; return (u16)((v.u + 0x7fffu + ((v.u>>16)&1u))>>16); }
DEV float bf2f(u16 b){ union{uint u;float f;} v; v.u=((uint)b)<<16; return v.f; }
DEV int imin(int a,int b){ return a<b?a:b; }

// ---------------- fused converts ----------------
__global__ void cvt_all(
    const float* __restrict__ hs, const float* __restrict__ wqa, const float* __restrict__ iwqb,
    const float* __restrict__ iwk, const float* __restrict__ iwp,
    const float* __restrict__ wqbw, const float* __restrict__ wkva, const float* __restrict__ wkvb,
    const float* __restrict__ wow,
    u16* __restrict__ hid_hi, u16* __restrict__ hid_lo, u16* __restrict__ wqa_hi, u16* __restrict__ wqa_lo,
    u16* __restrict__ iwqb_hi, u16* __restrict__ iwqb_lo, u16* __restrict__ kiwp_hi, u16* __restrict__ kiwp_lo,
    u16* __restrict__ wqb_b, u16* __restrict__ wkva_b, u16* __restrict__ wkvb_b, u16* __restrict__ wo_b)
{
  int i = blockIdx.x*blockDim.x + threadIdx.x;
  int st = gridDim.x*blockDim.x;
  for(; i < 6537216; i += st){
    const float* src; u16 *dh, *dl=nullptr; int j; bool split;
    if(i < 1048576){ src=hs;   dh=hid_hi;  dl=hid_lo;  j=i;         split=true; }
    else if(i < 1835008){ src=wqa;  dh=wqa_hi;  dl=wqa_lo;  j=i-1048576; split=true; }
    else if(i < 3407872){ src=iwqb; dh=iwqb_hi; dl=iwqb_lo; j=i-1835008; split=true; }
    else if(i < 3473408){ src=iwk;  dh=kiwp_hi; dl=kiwp_lo; j=i-3407872; split=true; }
    else if(i < 3489792){ src=iwp;  dh=kiwp_hi+128*2048; dl=kiwp_lo+128*2048; j=i-3473408; split=true; }
    else if(i < 4669440){ src=wqbw; dh=wqb_b;  j=i-3489792; split=false; }
    else if(i < 4964352){ src=wkva; dh=wkva_b; j=i-4669440; split=false; }
    else if(i < 5488640){ src=wkvb; dh=wkvb_b; j=i-4964352; split=false; }
    else               { src=wow;  dh=wo_b;   j=i-5488640; split=false; }
    f32x4 x = reinterpret_cast<const f32x4*>(src)[j];
    u16x4 h;
    #pragma unroll
    for(int k=0;k<4;k++) h[k]=f2bf(x[k]);
    reinterpret_cast<u16x4*>(dh)[j]=h;
    if(split){
      u16x4 l;
      #pragma unroll
      for(int k=0;k<4;k++) l[k]=f2bf(x[k]-bf2f(h[k]));
      reinterpret_cast<u16x4*>(dl)[j]=l;
    }
  }
}

// ---------------- GEMM (glds staging + T2 XOR swizzle, m97 structure) ----------------
// EPI=0: plain f32 store (with split-K plane). EPI=1: fused q-rope + log2e/sqrt(192) scale + bf16 store.
template<int BK>
DEV void stageT(const u16* __restrict__ gbase, int ld, int row0, int maxrow, int k0, u16* lds){
  int tid = threadIdx.x, w = tid>>6, l = tid&63;
  if(BK==32){
    #pragma unroll
    for(int j=0;j<2;j++){
      int seg = w + j*4;
      int row = seg*16 + (l>>2);
      int gr = row0 + row; if(gr > maxrow) gr = maxrow;
      int u = (l&3) ^ ((l>>2)&3);
      GLDS(gbase + (size_t)gr*ld + k0 + u*8, lds + seg*512);
    }
  } else { // BK==64
    #pragma unroll
    for(int j=0;j<4;j++){
      int c = w + j*4;
      int row = c*8 + (l>>3);
      int gr = row0 + row; if(gr > maxrow) gr = maxrow;
      int u = (l&7) ^ ((l>>3)&7);
      GLDS(gbase + (size_t)gr*ld + k0 + u*8, lds + c*512);
    }
  }
}

template<int SPLIT, int BK, int EPI>
__global__ __launch_bounds__(256,2) void gemm_glds(
    const u16* __restrict__ Ah, const u16* __restrict__ Al, int lda,
    const u16* __restrict__ Bh, const u16* __restrict__ Bl, int ldb,
    float* __restrict__ C, int ldc, int M, int N, int K,
    u16* __restrict__ O1, const float* __restrict__ fcos, const float* __restrict__ fsin)
{
  __shared__ u16 sAh[128*BK];
  __shared__ u16 sBh[128*BK];
  __shared__ u16 sAl[SPLIT?128*BK:8];
  __shared__ u16 sBl[SPLIT?128*BK:8];
  const int tid = threadIdx.x;
  const int w = tid>>6, l = tid&63;
  const int wr = w>>1, wc = w&1;
  const int l15 = l&15, l16 = l>>4;
  const int UM = BK/8 - 1;

  int gx = gridDim.x;
  int nwg = gx*gridDim.y;
  int orig = blockIdx.x + gx*blockIdx.y;
  int qq = nwg>>3, rr = nwg&7, xc = orig&7, oo = orig>>3;
  int wg = (xc<rr ? xc*(qq+1) : rr*(qq+1)+(xc-rr)*qq) + oo;
  int m0 = (wg/gx)*128, n0 = (wg%gx)*128;

  int kz = K/(int)gridDim.z;
  int kbeg = blockIdx.z*kz;

  f32x4 acc[4][4];
  #pragma unroll
  for(int m=0;m<4;m++)
    #pragma unroll
    for(int n=0;n<4;n++) acc[m][n] = f32x4{0.f,0.f,0.f,0.f};

  for(int k0=kbeg; k0<kbeg+kz; k0+=BK){
    __syncthreads();
    stageT<BK>(Ah, lda, m0, M-1, k0, sAh);
    stageT<BK>(Bh, ldb, n0, N-1, k0, sBh);
    if(SPLIT){
      stageT<BK>(Al, lda, m0, M-1, k0, sAl);
      stageT<BK>(Bl, ldb, n0, N-1, k0, sBl);
    }
    asm volatile("s_waitcnt vmcnt(0)" ::: "memory");
    __syncthreads();
    #pragma unroll
    for(int kk=0;kk<BK/32;kk++){
      bf16x8 ah[4], bh[4];
      #pragma unroll
      for(int m=0;m<4;m++){
        int row = wr*64+m*16+l15;
        ah[m] = *reinterpret_cast<const bf16x8*>(&sAh[row*BK + ((kk*4+l16)^(row&UM))*8]);
      }
      #pragma unroll
      for(int n=0;n<4;n++){
        int row = wc*64+n*16+l15;
        bh[n] = *reinterpret_cast<const bf16x8*>(&sBh[row*BK + ((kk*4+l16)^(row&UM))*8]);
      }
      #pragma unroll
      for(int m=0;m<4;m++)
        #pragma unroll
        for(int n=0;n<4;n++) acc[m][n] = MFMA(ah[m], bh[n], acc[m][n]);
      if(SPLIT){
        bf16x8 t[4];
        #pragma unroll
        for(int n=0;n<4;n++){
          int row = wc*64+n*16+l15;
          t[n] = *reinterpret_cast<const bf16x8*>(&sBl[row*BK + ((kk*4+l16)^(row&UM))*8]);
        }
        #pragma unroll
        for(int m=0;m<4;m++)
          #pragma unroll
          for(int n=0;n<4;n++) acc[m][n] = MFMA(ah[m], t[n], acc[m][n]);
        #pragma unroll
        for(int m=0;m<4;m++){
          int row = wr*64+m*16+l15;
          t[m] = *reinterpret_cast<const bf16x8*>(&sAl[row*BK + ((kk*4+l16)^(row&UM))*8]);
        }
        #pragma unroll
        for(int m=0;m<4;m++)
          #pragma unroll
          for(int n=0;n<4;n++) acc[m][n] = MFMA(t[m], bh[n], acc[m][n]);
      }
    }
  }
  if(EPI==0){
    float* Cp = C + (size_t)blockIdx.z*M*ldc;
    #pragma unroll
    for(int m=0;m<4;m++){
      int row = m0 + wr*64 + m*16 + l16*4;
      #pragma unroll
      for(int n=0;n<4;n++){
        int col = n0 + wc*64 + n*16 + l15;
        if(col < N){
          #pragma unroll
          for(int r=0;r<4;r++){
            int rrow = row + r;
            if(rrow < M) Cp[(size_t)rrow*ldc + col] = acc[m][n][r];
          }
        }
      }
    }
  } else {
    // EPI==1: fused q-rope (interleaved pairs = xor-adjacent lanes) + scale + bf16
    const float qsc = 0.10411756f;   // log2(e)/sqrt(192)
    #pragma unroll
    for(int m=0;m<4;m++){
      int rowb = m0 + wr*64 + m*16 + l16*4;
      #pragma unroll
      for(int n=0;n<4;n++){
        int col = n0 + wc*64 + n*16 + l15;
        int hq = col/192;
        int d  = col - hq*192;
        #pragma unroll
        for(int r=0;r<4;r++){
          int row = rowb + r;
          float v = acc[m][n][r];
          float p = __shfl_xor(v, 1, 64);   // pair partner (co-active: d parity == lane parity)
          float vv;
          if(d < 128) vv = v;
          else{
            int i2 = (d-128)>>1;
            float c0 = fcos[row*32 + i2], s_ = fsin[row*32 + i2];
            vv = ((d&1)==0) ? (v*c0 - p*s_) : (p*s_ + v*c0);
          }
          O1[(size_t)row*3072 + col] = f2bf(vv*qsc);
        }
      }
    }
  }
}

// ---------------- norms / rope ----------------
__global__ __launch_bounds__(256) void rmsnorm_qr_split(
    const float* __restrict__ in, const float* __restrict__ w,
    u16* __restrict__ hi, u16* __restrict__ lo)
{
  int s = blockIdx.x, tid = threadIdx.x;
  __shared__ float red[4];
  const float* x = in + (size_t)s*1536;
  const size_t plane = 2048ull*1536;
  float xv[6]; float ss=0.f;
  #pragma unroll
  for(int i=0;i<6;i++){ int c = tid+i*256; xv[i] = x[c] + x[plane+c]; ss += xv[i]*xv[i]; }
  #pragma unroll
  for(int o=32;o>0;o>>=1) ss += __shfl_down(ss,o,64);
  if((tid&63)==0) red[tid>>6]=ss;
  __syncthreads();
  float total = red[0]+red[1]+red[2]+red[3];
  float scale = rsqrtf(total*(1.0f/1536.0f) + 1e-6f);
  #pragma unroll
  for(int i=0;i<6;i++){
    int c = tid + i*256;
    float vv = xv[i]*scale*w[c];
    u16 hv = f2bf(vv);
    hi[(size_t)s*1536+c]=hv;
    lo[(size_t)s*1536+c]=f2bf(vv - bf2f(hv));
  }
}

__global__ __launch_bounds__(256) void kv_norm_rope(
    const float* __restrict__ kva, const float* __restrict__ w,
    const float* __restrict__ fcos, const float* __restrict__ fsin,
    u16* __restrict__ kvb, float* __restrict__ kpe)
{
  int s = blockIdx.x, tid = threadIdx.x;
  __shared__ float red[4];
  const size_t plane = 2048ull*576;
  float xv[2]={0.f,0.f};
  #pragma unroll
  for(int c=0;c<4;c++){
    const float* xp = kva + (size_t)c*plane + (size_t)s*576;
    xv[0]+=xp[tid]; xv[1]+=xp[tid+256];
  }
  float ss = xv[0]*xv[0]+xv[1]*xv[1];
  #pragma unroll
  for(int o=32;o>0;o>>=1) ss += __shfl_down(ss,o,64);
  if((tid&63)==0) red[tid>>6]=ss;
  __syncthreads();
  float total = red[0]+red[1]+red[2]+red[3];
  float scale = rsqrtf(total*(1.0f/512.0f)+1e-6f);
  #pragma unroll
  for(int i=0;i<2;i++){ int c=tid+i*256; kvb[(size_t)s*512+c]=f2bf(xv[i]*scale*w[c]); }
  if(tid<32){
    float x0=0.f, x1=0.f;
    #pragma unroll
    for(int c=0;c<4;c++){
      const float* xp = kva + (size_t)c*plane + (size_t)s*576;
      x0 += xp[512+2*tid]; x1 += xp[513+2*tid];
    }
    float c0=fcos[(size_t)s*32+tid], s_=fsin[(size_t)s*32+tid];
    kpe[(size_t)s*64+2*tid]   = x0*c0 - x1*s_;
    kpe[(size_t)s*64+2*tid+1] = x0*s_ + x1*c0;
  }
}

__global__ __launch_bounds__(256) void qi_rope_split(const float* __restrict__ qpre,
    const float* __restrict__ fcos, const float* __restrict__ fsin,
    u16* __restrict__ hi, u16* __restrict__ lo)
{
  int s = blockIdx.x;
  const float* rowp = qpre + (size_t)s*4096;
  for(int idx=threadIdx.x; idx<4096; idx+=256){
    int hh = idx>>7, d = idx&127;
    const float* hb = rowp + (hh<<7);
    float vv;
    if(d<32){ float c0=fcos[(size_t)s*32+d], s_=fsin[(size_t)s*32+d]; vv = hb[d]*c0 - hb[d+32]*s_; }
    else if(d<64){ int i2=d-32; float c0=fcos[(size_t)s*32+i2], s_=fsin[(size_t)s*32+i2]; vv = hb[i2]*s_ + hb[d]*c0; }
    else vv = hb[d];
    u16 hv = f2bf(vv);
    hi[(size_t)s*4096+idx]=hv;
    lo[(size_t)s*4096+idx]=f2bf(vv - bf2f(hv));
  }
}

__global__ __launch_bounds__(128) void ki_ln_rope_split(
    const float* __restrict__ kpre, const float* __restrict__ w, const float* __restrict__ bb,
    const float* __restrict__ fcos, const float* __restrict__ fsin,
    u16* __restrict__ hi, u16* __restrict__ lo, float* __restrict__ wts_out)
{
  int s = blockIdx.x, tid = threadIdx.x;
  __shared__ float red[2];
  __shared__ float ybuf[128];
  const size_t plane = 2048ull*160;
  float x = 0.f;
  #pragma unroll
  for(int c=0;c<8;c++) x += kpre[(size_t)c*plane + (size_t)s*160 + tid];
  if(tid<32){
    float ws = 0.f;
    #pragma unroll
    for(int c=0;c<8;c++) ws += kpre[(size_t)c*plane + (size_t)s*160 + 128 + tid];
    wts_out[(size_t)s*160 + 128 + tid] = ws;
  }
  float v = x;
  #pragma unroll
  for(int o=32;o>0;o>>=1) v += __shfl_down(v,o,64);
  if((tid&63)==0) red[tid>>6]=v;
  __syncthreads();
  float mean = (red[0]+red[1])*(1.f/128.f);
  __syncthreads();
  float dx = x - mean;
  v = dx*dx;
  #pragma unroll
  for(int o=32;o>0;o>>=1) v += __shfl_down(v,o,64);
  if((tid&63)==0) red[tid>>6]=v;
  __syncthreads();
  float var = (red[0]+red[1])*(1.f/128.f);
  float y = dx*rsqrtf(var+1e-5f)*w[tid] + bb[tid];
  ybuf[tid]=y;
  __syncthreads();
  float r;
  if(tid<32){ float c0=fcos[(size_t)s*32+tid], s_=fsin[(size_t)s*32+tid]; r = ybuf[tid]*c0 - ybuf[tid+32]*s_; }
  else if(tid<64){ int i2=tid-32; float c0=fcos[(size_t)s*32+i2], s_=fsin[(size_t)s*32+i2]; r = ybuf[i2]*s_ + ybuf[tid]*c0; }
  else r = y;
  u16 hv=f2bf(r);
  hi[(size_t)s*128+tid]=hv;
  lo[(size_t)s*128+tid]=f2bf(r-bf2f(hv));
}

// transpose V + assemble K in one kernel. grid (32, 16)
__global__ __launch_bounds__(256) void transpose_assemble(const float* __restrict__ kvp,
    const float* __restrict__ kpe, u16* __restrict__ vt, u16* __restrict__ kb){
  __shared__ u16 T[64*136];
  int s0 = blockIdx.x*64, h = blockIdx.y;
  int tid = threadIdx.x;
  for(int idx=tid; idx<64*192; idx+=256){
    int r = idx/192, d = idx - r*192;
    float val = (d<128) ? kvp[(size_t)(s0+r)*4096 + h*256 + d] : kpe[(size_t)(s0+r)*64 + (d-128)];
    kb[((size_t)(s0+r)*16 + h)*192 + d] = f2bf(val);
  }
  #pragma unroll
  for(int i=0;i<8;i++){
    int ch = i*256 + tid;
    int r = ch>>5, cc = ch&31;
    f32x4 x = *reinterpret_cast<const f32x4*>(&kvp[(size_t)(s0+r)*4096 + h*256 + 128 + cc*4]);
    u16x4 y;
    #pragma unroll
    for(int j=0;j<4;j++) y[j] = f2bf(x[j]);
    *reinterpret_cast<u16x4*>(&T[r*136 + cc*4]) = y;
  }
  __syncthreads();
  #pragma unroll
  for(int i=0;i<4;i++){
    int ch = i*256 + tid;
    int d = ch>>3, sc = ch&7;
    u16x8 y;
    #pragma unroll
    for(int j=0;j<8;j++) y[j] = T[(sc*8+j)*136 + d];
    *reinterpret_cast<u16x8*>(&vt[((size_t)h*128 + d)*2048 + s0 + sc*8]) = y;
  }
}

// ---------------- fused indexer scores v8 (best: 82us) ----------------
DEV void isc_pass64(const u16* __restrict__ Q, const u16* __restrict__ Kb,
                    f32x4 (&sc)[2][2], int wm, int wn, int l15, int l16){
  #pragma unroll
  for(int ks=0;ks<4;ks++){
    bf16x8 a[2], b[2];
    #pragma unroll
    for(int m=0;m<2;m++){
      int row = wm*32 + m*16 + l15;
      a[m] = *reinterpret_cast<const bf16x8*>(&Q[row*128 + ((((ks<<2)+l16) ^ (row&7))<<3)]);
    }
    #pragma unroll
    for(int n=0;n<2;n++){
      int row = wn*32 + n*16 + l15;
      b[n] = *reinterpret_cast<const bf16x8*>(&Kb[row*128 + ((((ks<<2)+l16) ^ (row&7))<<3)]);
    }
    #pragma unroll
    for(int m=0;m<2;m++)
      #pragma unroll
      for(int n=0;n<2;n++) sc[m][n] = MFMA(a[m], b[n], sc[m][n]);
  }
}

__global__ __launch_bounds__(512,4) void idx_scores7(
    const u16* __restrict__ qih, const u16* __restrict__ qil,
    const u16* __restrict__ kih, const u16* __restrict__ kil,
    const float* __restrict__ wts,
    float* __restrict__ p0, float* __restrict__ p1, float* __restrict__ p2, float* __restrict__ p3)
{
  __shared__ u16 Kh[128*128];
  __shared__ u16 Kl[128*128];
  __shared__ u16 Qb[64*128];
  int orig = blockIdx.x;
  int bid = (orig&7)*136 + (orig>>3);
  int tileIdx = bid>>2, hg = bid&3;
  int si=0, t=tileIdx;
  #pragma unroll 1
  for(; si<32; si++){ int cnt=(si+2)>>1; if(t<cnt) break; t-=cnt; }
  int s0 = si*64, t0 = t*128;
  float* plane = (hg==0)?p0:(hg==1)?p1:(hg==2)?p2:p3;
  float* outp = plane + (size_t)tileIdx*8192;
  int h0 = hg*8;
  int tid=threadIdx.x, w=tid>>6, l=tid&63;
  int wm=w>>2, wn=w&3, l15=l&15, l16=l>>4;
  const float cscale = 0.015625f;
  #pragma unroll
  for(int rnd=0;rnd<4;rnd++){
    int cid = rnd*512 + w*64 + l;
    int row = cid>>4, cc = cid&15;
    int scc = cc ^ (row&7);
    GLDS(kih + (size_t)(t0+row)*128 + scc*8, Kh + rnd*4096 + w*512);
    GLDS(kil + (size_t)(t0+row)*128 + scc*8, Kl + rnd*4096 + w*512);
  }
  #pragma unroll
  for(int rnd=0;rnd<2;rnd++){
    int cid = rnd*512 + w*64 + l;
    int row = cid>>4, cc = cid&15;
    int scc = cc ^ (row&7);
    GLDS(qih + (size_t)(s0+row)*4096 + h0*128 + scc*8, Qb + rnd*4096 + w*512);
  }
  asm volatile("s_waitcnt vmcnt(0)" ::: "memory");
  __syncthreads();
  f32x4 accI[2][2], sc[2][2];
  #pragma unroll
  for(int m=0;m<2;m++) for(int n=0;n<2;n++) accI[m][n] = f32x4{0.f,0.f,0.f,0.f};
  for(int s=0;s<16;s++){
    const u16* Q = Qb;
    if((s&1)==0){
      #pragma unroll
      for(int m=0;m<2;m++) for(int n=0;n<2;n++) sc[m][n] = f32x4{0.f,0.f,0.f,0.f};
      isc_pass64(Q, Kh, sc, wm, wn, l15, l16);
      isc_pass64(Q, Kl, sc, wm, wn, l15, l16);
    } else {
      isc_pass64(Q, Kh, sc, wm, wn, l15, l16);
      int hh = h0 + (s>>1);
      #pragma unroll
      for(int m=0;m<2;m++)
        #pragma unroll
        for(int r=0;r<4;r++){
          float wv = wts[(size_t)(s0+wm*32+m*16+l16*4+r)*160 + 128 + hh]*cscale;
          #pragma unroll
          for(int n=0;n<2;n++) accI[m][n][r] += fmaxf(sc[m][n][r],0.f)*wv;
        }
    }
    __syncthreads();
    int nxt = s+1;
    if(nxt < 16){
      const u16* src = (nxt&1) ? qil : qih;
      int hh = h0 + (nxt>>1);
      #pragma unroll
      for(int rnd=0;rnd<2;rnd++){
        int cid = rnd*512 + w*64 + l;
        int row = cid>>4, cc = cid&15;
        int scc = cc ^ (row&7);
        GLDS(src + (size_t)(s0+row)*4096 + hh*128 + scc*8, Qb + rnd*4096 + w*512);
      }
      asm volatile("s_waitcnt vmcnt(0)" ::: "memory");
      __syncthreads();
    }
  }
  #pragma unroll
  for(int m=0;m<2;m++)
    #pragma unroll
    for(int n=0;n<2;n++)
      #pragma unroll
      for(int r=0;r<4;r++)
        outp[(wm*32+m*16+l16*4+r)*128 + wn*32 + n*16 + l15] = accI[m][n][r];
}

// ---------------- exact top-512 per row -> bitmask ----------------
DEV uint fkey(float f){ union{float f;uint u;} v; v.f=f; return (v.u & 0x80000000u) ? ~v.u : (v.u | 0x80000000u); }

__global__ __launch_bounds__(256) void topk_mask(
    const float* __restrict__ p0, const float* __restrict__ p1,
    const float* __restrict__ p2, const float* __restrict__ p3, u64* __restrict__ bits)
{
  int s = blockIdx.x;
  int n = s+1;
  int tid = threadIdx.x;
  if(n <= 512){
    for(int wI=tid; wI<32; wI+=256){
      u64 m=0; int base=wI*64;
      if(base < n){ int cnt=n-base; m = (cnt>=64)? ~0ull : ((1ull<<cnt)-1ull); }
      bits[(size_t)s*32+wI]=m;
    }
    return;
  }
  __shared__ float row[2048];
  __shared__ uint hist[256];
  __shared__ uint sh_B, sh_k;
  __shared__ uint wcnt[32];
  int si = s>>6, sr = s&63;
  size_t triBase = (size_t)(((si+1)*(si+1))>>2);
  for(int c=tid; c<n; c+=256){
    size_t off = (triBase + (size_t)(c>>7))*8192 + (size_t)sr*128 + (c&127);
    row[c] = p0[off]+p1[off]+p2[off]+p3[off];
  }
  __syncthreads();
  uint prefix=0, k=512;
  for(int shift=24; shift>=0; shift-=8){
    hist[tid]=0;
    __syncthreads();
    for(int t2=tid;t2<n;t2+=256){
      uint u = fkey(row[t2]);
      bool ok = (shift==24) || ((u>>(shift+8)) == (prefix>>(shift+8)));
      if(ok) atomicAdd(&hist[(u>>shift)&255u],1u);
    }
    __syncthreads();
    for(int offd=1; offd<256; offd<<=1){
      uint add = (tid+offd<256)? hist[tid+offd] : 0u;
      __syncthreads();
      hist[tid] += add;
      __syncthreads();
    }
    uint nxtv = (tid<255)? hist[tid+1] : 0u;
    if(hist[tid]>=k && nxtv<k){ sh_B=(uint)tid; sh_k = k - nxtv; }
    __syncthreads();
    prefix |= sh_B<<shift;
    k = sh_k;
    __syncthreads();
  }
  uint thr = prefix;
  if(tid<32) wcnt[tid]=0;
  __syncthreads();
  int nw = (n+63)>>6;
  if(tid < nw){
    int base=tid*64, end = base+64; if(end>n) end=n;
    uint c=0;
    for(int t2=base;t2<end;t2++) if(fkey(row[t2])==thr) c++;
    wcnt[tid]=c;
  }
  __syncthreads();
  if(tid==0){
    uint runv=0;
    for(int i=0;i<32;i++){ uint c=wcnt[i]; wcnt[i]=runv; runv+=c; }
  }
  __syncthreads();
  if(tid<32){
    u64 m=0; int base=tid*64;
    if(base<n){
      uint rank = wcnt[tid];
      int end = base+64; if(end>n) end=n;
      for(int t2=base;t2<end;t2++){
        uint u = fkey(row[t2]);
        if(u>thr) m |= (1ull<<(t2-base));
        else if(u==thr){ if(rank<k) m |= (1ull<<(t2-base)); rank++; }
      }
    }
    bits[(size_t)s*32+tid]=m;
  }
}

// ---------------- flash attention: no-max exp2 softmax, 3 blocks/CU ----------------
__global__ __launch_bounds__(256,3) void flash_attn(
    const u16* __restrict__ q, const u16* __restrict__ k, const u16* __restrict__ vt,
    const u64* __restrict__ bits, u16* __restrict__ o,
    u16* __restrict__ Opart, float* __restrict__ ml)
{
  __shared__ u16 Ks[64*192];
  __shared__ u16 Vt[128*64];
  __shared__ u16 Pl[64*72];
  int h = blockIdx.y;
  int pp = blockIdx.x;
  int sblk=0, chunk=0;
  for(int i=0;i<32;i++){
    int sb = 31-i; int ncc = (sb>>3)+1;
    if(pp < ncc){ sblk=sb; chunk=pp; break; }
    pp -= ncc;
  }
  int nc = (sblk>>3)+1, ntiles = sblk+1, s0 = sblk*64;
  int tid=threadIdx.x, w=tid>>6, l=tid&63;
  int l15=l&15, l16=l>>4;
  bf16x8 qf[6];
  #pragma unroll
  for(int ks=0;ks<6;ks++)
    qf[ks] = *reinterpret_cast<const bf16x8*>(&q[((size_t)(s0+w*16+l15)*16 + h)*192 + ks*32 + l16*8]);
  f32x4 Oa[8];
  #pragma unroll
  for(int n=0;n<8;n++) Oa[n] = f32x4{0.f,0.f,0.f,0.f};
  float lrun[4];
  #pragma unroll
  for(int r=0;r<4;r++) lrun[r]=0.f;
  int tt0 = chunk*8, tt1 = imin(tt0+8, ntiles);
  for(int tt=tt0; tt<tt1; tt++){
    int t0 = tt*64;
    __syncthreads();
    #pragma unroll
    for(int rnd=0;rnd<6;rnd++){
      int cid = rnd*256 + w*64 + l;
      int row = cid/24, cc = cid - row*24;
      int scc = cc ^ (row&7);
      GLDS(k + ((size_t)(t0+row)*16 + h)*192 + scc*8, Ks + rnd*2048 + w*512);
    }
    #pragma unroll
    for(int rnd=0;rnd<4;rnd++){
      int cid = rnd*256 + w*64 + l;
      int row = cid>>3, cc = cid&7;
      int scc = cc ^ (row&7);
      GLDS(vt + ((size_t)h*128 + row)*2048 + t0 + scc*8, Vt + rnd*2048 + w*512);
    }
    asm volatile("s_waitcnt vmcnt(0)" ::: "memory");
    __syncthreads();
    f32x4 S[4];
    #pragma unroll
    for(int n=0;n<4;n++) S[n] = f32x4{0.f,0.f,0.f,0.f};
    #pragma unroll
    for(int ks=0;ks<6;ks++){
      bf16x8 b[4];
      #pragma unroll
      for(int n=0;n<4;n++){
        int row = n*16+l15;
        b[n] = *reinterpret_cast<const bf16x8*>(&Ks[row*192 + ((((ks<<2)+l16) ^ (row&7))<<3)]);
      }
      #pragma unroll
      for(int n=0;n<4;n++) S[n] = MFMA(qf[ks], b[n], S[n]);
    }
    bool diag = (tt == sblk);
    #pragma unroll
    for(int r=0;r<4;r++){
      int srow = s0 + w*16 + l16*4 + r;
      u64 wrd = bits[(size_t)srow*32 + (t0>>6)];
      if(diag) wrd &= (((1ull<<(srow&63))<<1) - 1ull);
      float rs = 0.f;
      #pragma unroll
      for(int n=0;n<4;n++){
        int bitp = n*16 + l15;
        bool ok = (wrd>>bitp)&1ull;
        float p = ok ? exp2f(S[n][r]) : 0.f;
        S[n][r] = p;
        rs += p;
      }
      #pragma unroll
      for(int off=1;off<16;off<<=1) rs += __shfl_xor(rs, off, 64);
      lrun[r] += rs;
    }
    #pragma unroll
    for(int n=0;n<4;n++)
      #pragma unroll
      for(int r=0;r<4;r++)
        Pl[(w*16+l16*4+r)*72 + n*16+l15] = f2bf(S[n][r]);
    #pragma unroll
    for(int ks=0;ks<2;ks++){
      bf16x8 a = *reinterpret_cast<const bf16x8*>(&Pl[(w*16+l15)*72 + ks*32 + l16*8]);
      bf16x8 bb[8];
      #pragma unroll
      for(int n=0;n<8;n++){
        int d = n*16+l15;
        bb[n] = *reinterpret_cast<const bf16x8*>(&Vt[d*64 + ((((ks<<2)+l16) ^ (d&7))<<3)]);
      }
      #pragma unroll
      for(int n=0;n<8;n++) Oa[n] = MFMA(a, bb[n], Oa[n]);
    }
  }
  if(nc == 1){
    #pragma unroll
    for(int r=0;r<4;r++){
      int srow = s0 + w*16 + l16*4 + r;
      float inv = 1.f/lrun[r];
      #pragma unroll
      for(int n=0;n<8;n++)
        o[(size_t)srow*2048 + h*128 + n*16 + l15] = f2bf(Oa[n][r]*inv);
    }
  } else {
    int part = ((h*32 + sblk)<<2) + chunk;
    u16* Op = Opart + (size_t)part*8192;
    #pragma unroll
    for(int r=0;r<4;r++){
      int rit = w*16 + l16*4 + r;
      #pragma unroll
      for(int n=0;n<8;n++)
        Op[rit*128 + n*16 + l15] = f2bf(Oa[n][r]);
      if(l15==0)
        ml[(size_t)part*128 + rit*2+1] = lrun[r];
    }
  }
}

__global__ __launch_bounds__(256) void flash_combine(
    const u16* __restrict__ Opart, const float* __restrict__ ml, u16* __restrict__ o)
{
  int b = blockIdx.x;
  int h = b/24, sblk = 8 + (b%24);
  int nc = (sblk>>3)+1;
  int tid = threadIdx.x;
  int r = tid>>2, dq = (tid&3)*32;
  int s0 = sblk*64;
  int pbase = (h*32+sblk)<<2;
  float L = 0.f;
  for(int c=0;c<nc;c++) L += ml[(size_t)(pbase+c)*128 + r*2 + 1];
  float inv = 1.f/L;
  for(int dd=0; dd<32; dd+=8){
    float accv[8];
    #pragma unroll
    for(int j=0;j<8;j++) accv[j]=0.f;
    for(int c=0;c<nc;c++){
      u16x8 pv = *reinterpret_cast<const u16x8*>(&Opart[(size_t)(pbase+c)*8192 + r*128 + dq + dd]);
      #pragma unroll
      for(int j=0;j<8;j++) accv[j] += bf2f(pv[j]);
    }
    u16x8 ov;
    #pragma unroll
    for(int j=0;j<8;j++) ov[j] = f2bf(accv[j]*inv);
    *reinterpret_cast<u16x8*>(&o[(size_t)(s0+r)*2048 + h*128 + dq + dd]) = ov;
  }
}

// ---------------- host ----------------
extern "C" void kernel_launch(void* const* d_in, const int* in_sizes, int n_in,
                              void* d_out, int out_size, void* d_ws, size_t ws_size,
                              hipStream_t stream)
{
  (void)in_sizes; (void)n_in; (void)out_size;
  const float* hs   = (const float*)d_in[0];
  const float* wqa  = (const float*)d_in[1];
  const float* qnw  = (const float*)d_in[2];
  const float* wqbw = (const float*)d_in[3];
  const float* wkva = (const float*)d_in[4];
  const float* kvnw = (const float*)d_in[5];
  const float* wkvb = (const float*)d_in[6];
  const float* wow  = (const float*)d_in[7];
  const float* iwqb = (const float*)d_in[8];
  const float* iwk  = (const float*)d_in[9];
  const float* iknw = (const float*)d_in[10];
  const float* iknb = (const float*)d_in[11];
  const float* iwp  = (const float*)d_in[12];
  const float* fcos = (const float*)d_in[13];
  const float* fsin = (const float*)d_in[14];
  float* outp = (float*)d_out;

  char* base = (char*)d_ws;
  size_t off = 0;
  auto alloc = [&](size_t bytes)->char*{ char* p = base+off; off += (bytes+255)&~(size_t)255; return p; };
  u16* hid_hi = (u16*)alloc(2048ull*2048*2);
  u16* hid_lo = (u16*)alloc(2048ull*2048*2);
  u16* wqa_hi = (u16*)alloc(1536ull*2048*2);
  u16* wqa_lo = (u16*)alloc(1536ull*2048*2);
  u16* wqb_b  = (u16*)alloc(3072ull*1536*2);
  u16* wkva_b = (u16*)alloc(576ull*2048*2);
  u16* wkvb_b = (u16*)alloc(4096ull*512*2);
  u16* wo_b   = (u16*)alloc(2048ull*2048*2);
  u16* iwqb_hi= (u16*)alloc(4096ull*1536*2);
  u16* iwqb_lo= (u16*)alloc(4096ull*1536*2);
  u16* kiwp_hi= (u16*)alloc(160ull*2048*2);
  u16* kiwp_lo= (u16*)alloc(160ull*2048*2);
  float* kiwp_C=(float*)alloc(2048ull*160*4);
  u16* qr_hi  = (u16*)alloc(2048ull*1536*2);
  u16* qr_lo  = (u16*)alloc(2048ull*1536*2);
  u16* kv_b   = (u16*)alloc(2048ull*512*2);
  float* kpe  = (float*)alloc(2048ull*64*4);
  u16* k_b    = (u16*)alloc(2048ull*16*192*2);
  u16* v_t    = (u16*)alloc(16ull*128*2048*2);
  u16* ki_hi  = (u16*)alloc(2048ull*128*2);
  u16* ki_lo  = (u16*)alloc(2048ull*128*2);
  u64* bits   = (u64*)alloc(2048ull*32*8);
  u16* attn_b = (u16*)alloc(2048ull*2048*2);
  float* reg1 = (float*)alloc(2048ull*4096*4);
  if(ws_size < off) return;

  // aliases (lifetime-checked)
  u16* q_b      = wqa_hi;            // spans wqa_hi+wqa_lo; wq_a dead after qr gemm; written by q-GEMM EPI=1
  u16* qi_hi    = hid_hi;            // spans hid_hi+hid_lo; hidden dead after kiwp gemm
  u16* qi_lo    = iwqb_hi;           // spans into iwqb_lo; idx_wq_b dead after qi gemm
  float* ml     = (float*)qr_lo;     // qr dead after qi gemm
  float* qr_pre = reg1;
  float* kva_part = reg1;
  float* kvp    = reg1;
  float* kiwp_part = reg1;
  float* qi_pre = reg1;
  const size_t PLANE = 272ull*8192;
  float* ip0 = reg1;
  float* ip1 = reg1 + PLANE;
  float* ip2 = reg1 + 2*PLANE;
  float* ip3 = (float*)wqb_b;        // wqb_b dead after q gemm
  u16* Opart = (u16*)reg1;

  auto G1 = [&](const u16* A,int lda,const u16* B,int ldb,float* C,int ldc,int M,int N,int K,int z){
    dim3 g((unsigned)((N+127)/128), (unsigned)((M+127)/128), (unsigned)z);
    gemm_glds<0,64,0><<<g,256,0,stream>>>(A,nullptr,lda,B,nullptr,ldb,C,ldc,M,N,K,nullptr,nullptr,nullptr);
  };
  auto G3 = [&](const u16* Ah,const u16* Al,int lda,const u16* Bh,const u16* Bl,int ldb,float* C,int ldc,int M,int N,int K,int z){
    dim3 g((unsigned)((N+127)/128), (unsigned)((M+127)/128), (unsigned)z);
    gemm_glds<1,64,0><<<g,256,0,stream>>>(Ah,Al,lda,Bh,Bl,ldb,C,ldc,M,N,K,nullptr,nullptr,nullptr);
  };

  cvt_all<<<2048,256,0,stream>>>(hs,wqa,iwqb,iwk,iwp,wqbw,wkva,wkvb,wow,
      hid_hi,hid_lo,wqa_hi,wqa_lo,iwqb_hi,iwqb_lo,kiwp_hi,kiwp_lo,
      wqb_b,wkva_b,wkvb_b,wo_b);

  // qr = rmsnorm(hidden @ wq_a^T), split-K z=2, plane-sum fused into rmsnorm
  G3(hid_hi,hid_lo,2048, wqa_hi,wqa_lo,2048, qr_pre,1536, 2048,1536,2048, 2);
  rmsnorm_qr_split<<<2048,256,0,stream>>>(qr_pre, qnw, qr_hi, qr_lo);

  // q path: GEMM with fused rope+scale+bf16 epilogue (writes q_b directly)
  {
    dim3 g(24, 16, 1);
    gemm_glds<0,64,1><<<g,256,0,stream>>>(qr_hi,nullptr,1536, wqb_b,nullptr,1536,
        nullptr,0, 2048,3072,1536, q_b, fcos, fsin);
  }

  // kv path (split-K z=4, plane-sum fused into kv_norm_rope)
  G1(hid_hi,2048, wkva_b,2048, kva_part,576, 2048,576,2048, 4);
  kv_norm_rope<<<2048,256,0,stream>>>(kva_part, kvnw, fcos, fsin, kv_b, kpe);
  G1(kv_b,512, wkvb_b,512, kvp,4096, 2048,4096,512, 1);
  transpose_assemble<<<dim3(32,16),256,0,stream>>>(kvp, kpe, v_t, k_b);

  // indexer ki + wts packed (N=160, split-K z=8)
  G3(hid_hi,hid_lo,2048, kiwp_hi,kiwp_lo,2048, kiwp_part,160, 2048,160,2048, 8);
  ki_ln_rope_split<<<2048,128,0,stream>>>(kiwp_part, iknw, iknb, fcos, fsin, ki_hi, ki_lo, kiwp_C);

  // indexer qi
  G3(qr_hi,qr_lo,1536, iwqb_hi,iwqb_lo,1536, qi_pre,4096, 2048,4096,1536, 1);
  qi_rope_split<<<2048,256,0,stream>>>(qi_pre, fcos, fsin, qi_hi, qi_lo);

  // fused index scores + topk
  idx_scores7<<<1088,512,0,stream>>>(qi_hi, qi_lo, ki_hi, ki_lo, kiwp_C, ip0, ip1, ip2, ip3);
  topk_mask<<<2048,256,0,stream>>>(ip0, ip1, ip2, ip3, bits);

  // attention + combine + output projection
  flash_attn<<<dim3(80,16),256,0,stream>>>(q_b, k_b, v_t, bits, attn_b, Opart, ml);
  flash_combine<<<384,256,0,stream>>>(Opart, ml, attn_b);
  G1(attn_b,2048, wo_b,2048, outp,2048, 2048,2048,2048, 1);
}

// Round 21
// 477.080 us; speedup vs baseline: 1.0063x; 1.0056x over previous
//
#include <hip/hip_runtime.h>
#include <stdint.h>

typedef unsigned int uint;
typedef unsigned short u16;
typedef unsigned long long u64;

typedef float  f32x4 __attribute__((ext_vector_type(4)));
typedef uint   u32x4 __attribute__((ext_vector_type(4)));
typedef u16    u16x4 __attribute__((ext_vector_type(4)));
typedef u16    u16x8 __attribute__((ext_vector_type(8)));
typedef __bf16 bf16x8 __attribute__((ext_vector_type(8)));

#define DEV static __device__ __forceinline__
#define MFMA(a,b,c) __builtin_amdgcn_mfma_f32_16x16x32_bf16((a),(b),(c),0,0,0)
#define GLDS(src,dst) __builtin_amdgcn_global_load_lds((const __attribute__((address_space(1))) void*)(src),(__attribute__((address_space(3))) void*)(dst),16,0,0)

DEV u16 f2bf(float x){ union{float f;uint u;} v; v.f=x; return (u16)((v.u + 0x7fffu + ((v.u>>16)&1u))>>16); }
DEV float bf2f(u16 b){ union{uint u;float f;} v; v.u=((uint)b)<<16; return v.f; }
DEV int imin(int a,int b){ return a<b?a:b; }

// ---------------- fused converts ----------------
__global__ void cvt_all(
    const float* __restrict__ hs, const float* __restrict__ wqa, const float* __restrict__ iwqb,
    const float* __restrict__ iwk, const float* __restrict__ iwp,
    const float* __restrict__ wqbw, const float* __restrict__ wkva, const float* __restrict__ wkvb,
    const float* __restrict__ wow,
    u16* __restrict__ hid_hi, u16* __restrict__ hid_lo, u16* __restrict__ wqa_hi, u16* __restrict__ wqa_lo,
    u16* __restrict__ iwqb_hi, u16* __restrict__ iwqb_lo, u16* __restrict__ kiwp_hi, u16* __restrict__ kiwp_lo,
    u16* __restrict__ wqb_b, u16* __restrict__ wkva_b, u16* __restrict__ wkvb_b, u16* __restrict__ wo_b)
{
  int i = blockIdx.x*blockDim.x + threadIdx.x;
  int st = gridDim.x*blockDim.x;
  for(; i < 6537216; i += st){
    const float* src; u16 *dh, *dl=nullptr; int j; bool split;
    if(i < 1048576){ src=hs;   dh=hid_hi;  dl=hid_lo;  j=i;         split=true; }
    else if(i < 1835008){ src=wqa;  dh=wqa_hi;  dl=wqa_lo;  j=i-1048576; split=true; }
    else if(i < 3407872){ src=iwqb; dh=iwqb_hi; dl=iwqb_lo; j=i-1835008; split=true; }
    else if(i < 3473408){ src=iwk;  dh=kiwp_hi; dl=kiwp_lo; j=i-3407872; split=true; }
    else if(i < 3489792){ src=iwp;  dh=kiwp_hi+128*2048; dl=kiwp_lo+128*2048; j=i-3473408; split=true; }
    else if(i < 4669440){ src=wqbw; dh=wqb_b;  j=i-3489792; split=false; }
    else if(i < 4964352){ src=wkva; dh=wkva_b; j=i-4669440; split=false; }
    else if(i < 5488640){ src=wkvb; dh=wkvb_b; j=i-4964352; split=false; }
    else               { src=wow;  dh=wo_b;   j=i-5488640; split=false; }
    f32x4 x = reinterpret_cast<const f32x4*>(src)[j];
    u16x4 h;
    #pragma unroll
    for(int k=0;k<4;k++) h[k]=f2bf(x[k]);
    reinterpret_cast<u16x4*>(dh)[j]=h;
    if(split){
      u16x4 l;
      #pragma unroll
      for(int k=0;k<4;k++) l[k]=f2bf(x[k]-bf2f(h[k]));
      reinterpret_cast<u16x4*>(dl)[j]=l;
    }
  }
}

// ---------------- GEMM (glds staging + T2 XOR swizzle, m97 structure) ----------------
// EPI=0: plain f32 store (with split-K plane). EPI=1: fused q-rope + log2e/sqrt(192) scale + bf16 store.
template<int BK>
DEV void stageT(const u16* __restrict__ gbase, int ld, int row0, int maxrow, int k0, u16* lds){
  int tid = threadIdx.x, w = tid>>6, l = tid&63;
  if(BK==32){
    #pragma unroll
    for(int j=0;j<2;j++){
      int seg = w + j*4;
      int row = seg*16 + (l>>2);
      int gr = row0 + row; if(gr > maxrow) gr = maxrow;
      int u = (l&3) ^ ((l>>2)&3);
      GLDS(gbase + (size_t)gr*ld + k0 + u*8, lds + seg*512);
    }
  } else { // BK==64
    #pragma unroll
    for(int j=0;j<4;j++){
      int c = w + j*4;
      int row = c*8 + (l>>3);
      int gr = row0 + row; if(gr > maxrow) gr = maxrow;
      int u = (l&7) ^ ((l>>3)&7);
      GLDS(gbase + (size_t)gr*ld + k0 + u*8, lds + c*512);
    }
  }
}

template<int SPLIT, int BK, int EPI>
__global__ __launch_bounds__(256,2) void gemm_glds(
    const u16* __restrict__ Ah, const u16* __restrict__ Al, int lda,
    const u16* __restrict__ Bh, const u16* __restrict__ Bl, int ldb,
    float* __restrict__ C, int ldc, int M, int N, int K,
    u16* __restrict__ O1, const float* __restrict__ fcos, const float* __restrict__ fsin)
{
  __shared__ u16 sAh[128*BK];
  __shared__ u16 sBh[128*BK];
  __shared__ u16 sAl[SPLIT?128*BK:8];
  __shared__ u16 sBl[SPLIT?128*BK:8];
  const int tid = threadIdx.x;
  const int w = tid>>6, l = tid&63;
  const int wr = w>>1, wc = w&1;
  const int l15 = l&15, l16 = l>>4;
  const int UM = BK/8 - 1;

  int gx = gridDim.x;
  int nwg = gx*gridDim.y;
  int orig = blockIdx.x + gx*blockIdx.y;
  int qq = nwg>>3, rr = nwg&7, xc = orig&7, oo = orig>>3;
  int wg = (xc<rr ? xc*(qq+1) : rr*(qq+1)+(xc-rr)*qq) + oo;
  int m0 = (wg/gx)*128, n0 = (wg%gx)*128;

  int kz = K/(int)gridDim.z;
  int kbeg = blockIdx.z*kz;

  f32x4 acc[4][4];
  #pragma unroll
  for(int m=0;m<4;m++)
    #pragma unroll
    for(int n=0;n<4;n++) acc[m][n] = f32x4{0.f,0.f,0.f,0.f};

  for(int k0=kbeg; k0<kbeg+kz; k0+=BK){
    __syncthreads();
    stageT<BK>(Ah, lda, m0, M-1, k0, sAh);
    stageT<BK>(Bh, ldb, n0, N-1, k0, sBh);
    if(SPLIT){
      stageT<BK>(Al, lda, m0, M-1, k0, sAl);
      stageT<BK>(Bl, ldb, n0, N-1, k0, sBl);
    }
    asm volatile("s_waitcnt vmcnt(0)" ::: "memory");
    __syncthreads();
    #pragma unroll
    for(int kk=0;kk<BK/32;kk++){
      bf16x8 ah[4], bh[4];
      #pragma unroll
      for(int m=0;m<4;m++){
        int row = wr*64+m*16+l15;
        ah[m] = *reinterpret_cast<const bf16x8*>(&sAh[row*BK + ((kk*4+l16)^(row&UM))*8]);
      }
      #pragma unroll
      for(int n=0;n<4;n++){
        int row = wc*64+n*16+l15;
        bh[n] = *reinterpret_cast<const bf16x8*>(&sBh[row*BK + ((kk*4+l16)^(row&UM))*8]);
      }
      #pragma unroll
      for(int m=0;m<4;m++)
        #pragma unroll
        for(int n=0;n<4;n++) acc[m][n] = MFMA(ah[m], bh[n], acc[m][n]);
      if(SPLIT){
        bf16x8 t[4];
        #pragma unroll
        for(int n=0;n<4;n++){
          int row = wc*64+n*16+l15;
          t[n] = *reinterpret_cast<const bf16x8*>(&sBl[row*BK + ((kk*4+l16)^(row&UM))*8]);
        }
        #pragma unroll
        for(int m=0;m<4;m++)
          #pragma unroll
          for(int n=0;n<4;n++) acc[m][n] = MFMA(ah[m], t[n], acc[m][n]);
        #pragma unroll
        for(int m=0;m<4;m++){
          int row = wr*64+m*16+l15;
          t[m] = *reinterpret_cast<const bf16x8*>(&sAl[row*BK + ((kk*4+l16)^(row&UM))*8]);
        }
        #pragma unroll
        for(int m=0;m<4;m++)
          #pragma unroll
          for(int n=0;n<4;n++) acc[m][n] = MFMA(t[m], bh[n], acc[m][n]);
      }
    }
  }
  if(EPI==0){
    float* Cp = C + (size_t)blockIdx.z*M*ldc;
    #pragma unroll
    for(int m=0;m<4;m++){
      int row = m0 + wr*64 + m*16 + l16*4;
      #pragma unroll
      for(int n=0;n<4;n++){
        int col = n0 + wc*64 + n*16 + l15;
        if(col < N){
          #pragma unroll
          for(int r=0;r<4;r++){
            int rrow = row + r;
            if(rrow < M) Cp[(size_t)rrow*ldc + col] = acc[m][n][r];
          }
        }
      }
    }
  } else {
    // EPI==1: fused q-rope (interleaved pairs = xor-adjacent lanes) + scale + bf16
    const float qsc = 0.10411756f;   // log2(e)/sqrt(192)
    #pragma unroll
    for(int m=0;m<4;m++){
      int rowb = m0 + wr*64 + m*16 + l16*4;
      #pragma unroll
      for(int n=0;n<4;n++){
        int col = n0 + wc*64 + n*16 + l15;
        int hq = col/192;
        int d  = col - hq*192;
        #pragma unroll
        for(int r=0;r<4;r++){
          int row = rowb + r;
          float v = acc[m][n][r];
          float p = __shfl_xor(v, 1, 64);   // pair partner (co-active: d parity == lane parity)
          float vv;
          if(d < 128) vv = v;
          else{
            int i2 = (d-128)>>1;
            float c0 = fcos[row*32 + i2], s_ = fsin[row*32 + i2];
            vv = ((d&1)==0) ? (v*c0 - p*s_) : (p*s_ + v*c0);
          }
          O1[(size_t)row*3072 + col] = f2bf(vv*qsc);
        }
      }
    }
  }
}

// ---------------- norms / rope ----------------
__global__ __launch_bounds__(256) void rmsnorm_qr_split(
    const float* __restrict__ in, const float* __restrict__ w,
    u16* __restrict__ hi, u16* __restrict__ lo)
{
  int s = blockIdx.x, tid = threadIdx.x;
  __shared__ float red[4];
  const float* x = in + (size_t)s*1536;
  const size_t plane = 2048ull*1536;
  float xv[6]; float ss=0.f;
  #pragma unroll
  for(int i=0;i<6;i++){ int c = tid+i*256; xv[i] = x[c] + x[plane+c]; ss += xv[i]*xv[i]; }
  #pragma unroll
  for(int o=32;o>0;o>>=1) ss += __shfl_down(ss,o,64);
  if((tid&63)==0) red[tid>>6]=ss;
  __syncthreads();
  float total = red[0]+red[1]+red[2]+red[3];
  float scale = rsqrtf(total*(1.0f/1536.0f) + 1e-6f);
  #pragma unroll
  for(int i=0;i<6;i++){
    int c = tid + i*256;
    float vv = xv[i]*scale*w[c];
    u16 hv = f2bf(vv);
    hi[(size_t)s*1536+c]=hv;
    lo[(size_t)s*1536+c]=f2bf(vv - bf2f(hv));
  }
}

__global__ __launch_bounds__(256) void kv_norm_rope(
    const float* __restrict__ kva, const float* __restrict__ w,
    const float* __restrict__ fcos, const float* __restrict__ fsin,
    u16* __restrict__ kvb, float* __restrict__ kpe)
{
  int s = blockIdx.x, tid = threadIdx.x;
  __shared__ float red[4];
  const size_t plane = 2048ull*576;
  float xv[2]={0.f,0.f};
  #pragma unroll
  for(int c=0;c<4;c++){
    const float* xp = kva + (size_t)c*plane + (size_t)s*576;
    xv[0]+=xp[tid]; xv[1]+=xp[tid+256];
  }
  float ss = xv[0]*xv[0]+xv[1]*xv[1];
  #pragma unroll
  for(int o=32;o>0;o>>=1) ss += __shfl_down(ss,o,64);
  if((tid&63)==0) red[tid>>6]=ss;
  __syncthreads();
  float total = red[0]+red[1]+red[2]+red[3];
  float scale = rsqrtf(total*(1.0f/512.0f)+1e-6f);
  #pragma unroll
  for(int i=0;i<2;i++){ int c=tid+i*256; kvb[(size_t)s*512+c]=f2bf(xv[i]*scale*w[c]); }
  if(tid<32){
    float x0=0.f, x1=0.f;
    #pragma unroll
    for(int c=0;c<4;c++){
      const float* xp = kva + (size_t)c*plane + (size_t)s*576;
      x0 += xp[512+2*tid]; x1 += xp[513+2*tid];
    }
    float c0=fcos[(size_t)s*32+tid], s_=fsin[(size_t)s*32+tid];
    kpe[(size_t)s*64+2*tid]   = x0*c0 - x1*s_;
    kpe[(size_t)s*64+2*tid+1] = x0*s_ + x1*c0;
  }
}

__global__ __launch_bounds__(256) void qi_rope_split(const float* __restrict__ qpre,
    const float* __restrict__ fcos, const float* __restrict__ fsin,
    u16* __restrict__ hi, u16* __restrict__ lo)
{
  int s = blockIdx.x;
  const float* rowp = qpre + (size_t)s*4096;
  for(int idx=threadIdx.x; idx<4096; idx+=256){
    int hh = idx>>7, d = idx&127;
    const float* hb = rowp + (hh<<7);
    float vv;
    if(d<32){ float c0=fcos[(size_t)s*32+d], s_=fsin[(size_t)s*32+d]; vv = hb[d]*c0 - hb[d+32]*s_; }
    else if(d<64){ int i2=d-32; float c0=fcos[(size_t)s*32+i2], s_=fsin[(size_t)s*32+i2]; vv = hb[i2]*s_ + hb[d]*c0; }
    else vv = hb[d];
    u16 hv = f2bf(vv);
    hi[(size_t)s*4096+idx]=hv;
    lo[(size_t)s*4096+idx]=f2bf(vv - bf2f(hv));
  }
}

__global__ __launch_bounds__(128) void ki_ln_rope_split(
    const float* __restrict__ kpre, const float* __restrict__ w, const float* __restrict__ bb,
    const float* __restrict__ fcos, const float* __restrict__ fsin,
    u16* __restrict__ hi, u16* __restrict__ lo, float* __restrict__ wts_out)
{
  int s = blockIdx.x, tid = threadIdx.x;
  __shared__ float red[2];
  __shared__ float ybuf[128];
  const size_t plane = 2048ull*160;
  float x = 0.f;
  #pragma unroll
  for(int c=0;c<8;c++) x += kpre[(size_t)c*plane + (size_t)s*160 + tid];
  if(tid<32){
    float ws = 0.f;
    #pragma unroll
    for(int c=0;c<8;c++) ws += kpre[(size_t)c*plane + (size_t)s*160 + 128 + tid];
    wts_out[(size_t)s*160 + 128 + tid] = ws;
  }
  float v = x;
  #pragma unroll
  for(int o=32;o>0;o>>=1) v += __shfl_down(v,o,64);
  if((tid&63)==0) red[tid>>6]=v;
  __syncthreads();
  float mean = (red[0]+red[1])*(1.f/128.f);
  __syncthreads();
  float dx = x - mean;
  v = dx*dx;
  #pragma unroll
  for(int o=32;o>0;o>>=1) v += __shfl_down(v,o,64);
  if((tid&63)==0) red[tid>>6]=v;
  __syncthreads();
  float var = (red[0]+red[1])*(1.f/128.f);
  float y = dx*rsqrtf(var+1e-5f)*w[tid] + bb[tid];
  ybuf[tid]=y;
  __syncthreads();
  float r;
  if(tid<32){ float c0=fcos[(size_t)s*32+tid], s_=fsin[(size_t)s*32+tid]; r = ybuf[tid]*c0 - ybuf[tid+32]*s_; }
  else if(tid<64){ int i2=tid-32; float c0=fcos[(size_t)s*32+i2], s_=fsin[(size_t)s*32+i2]; r = ybuf[i2]*s_ + ybuf[tid]*c0; }
  else r = y;
  u16 hv=f2bf(r);
  hi[(size_t)s*128+tid]=hv;
  lo[(size_t)s*128+tid]=f2bf(r-bf2f(hv));
}

// transpose V + assemble K in one kernel. grid (32, 16)
__global__ __launch_bounds__(256) void transpose_assemble(const float* __restrict__ kvp,
    const float* __restrict__ kpe, u16* __restrict__ vt, u16* __restrict__ kb){
  __shared__ u16 T[64*136];
  int s0 = blockIdx.x*64, h = blockIdx.y;
  int tid = threadIdx.x;
  for(int idx=tid; idx<64*192; idx+=256){
    int r = idx/192, d = idx - r*192;
    float val = (d<128) ? kvp[(size_t)(s0+r)*4096 + h*256 + d] : kpe[(size_t)(s0+r)*64 + (d-128)];
    kb[((size_t)(s0+r)*16 + h)*192 + d] = f2bf(val);
  }
  #pragma unroll
  for(int i=0;i<8;i++){
    int ch = i*256 + tid;
    int r = ch>>5, cc = ch&31;
    f32x4 x = *reinterpret_cast<const f32x4*>(&kvp[(size_t)(s0+r)*4096 + h*256 + 128 + cc*4]);
    u16x4 y;
    #pragma unroll
    for(int j=0;j<4;j++) y[j] = f2bf(x[j]);
    *reinterpret_cast<u16x4*>(&T[r*136 + cc*4]) = y;
  }
  __syncthreads();
  #pragma unroll
  for(int i=0;i<4;i++){
    int ch = i*256 + tid;
    int d = ch>>3, sc = ch&7;
    u16x8 y;
    #pragma unroll
    for(int j=0;j<8;j++) y[j] = T[(sc*8+j)*136 + d];
    *reinterpret_cast<u16x8*>(&vt[((size_t)h*128 + d)*2048 + s0 + sc*8]) = y;
  }
}

// ---------------- fused indexer scores v8 (best: 82us) ----------------
DEV void isc_pass64(const u16* __restrict__ Q, const u16* __restrict__ Kb,
                    f32x4 (&sc)[2][2], int wm, int wn, int l15, int l16){
  #pragma unroll
  for(int ks=0;ks<4;ks++){
    bf16x8 a[2], b[2];
    #pragma unroll
    for(int m=0;m<2;m++){
      int row = wm*32 + m*16 + l15;
      a[m] = *reinterpret_cast<const bf16x8*>(&Q[row*128 + ((((ks<<2)+l16) ^ (row&7))<<3)]);
    }
    #pragma unroll
    for(int n=0;n<2;n++){
      int row = wn*32 + n*16 + l15;
      b[n] = *reinterpret_cast<const bf16x8*>(&Kb[row*128 + ((((ks<<2)+l16) ^ (row&7))<<3)]);
    }
    #pragma unroll
    for(int m=0;m<2;m++)
      #pragma unroll
      for(int n=0;n<2;n++) sc[m][n] = MFMA(a[m], b[n], sc[m][n]);
  }
}

__global__ __launch_bounds__(512,4) void idx_scores7(
    const u16* __restrict__ qih, const u16* __restrict__ qil,
    const u16* __restrict__ kih, const u16* __restrict__ kil,
    const float* __restrict__ wts,
    float* __restrict__ p0, float* __restrict__ p1, float* __restrict__ p2, float* __restrict__ p3)
{
  __shared__ u16 Kh[128*128];
  __shared__ u16 Kl[128*128];
  __shared__ u16 Qb[64*128];
  int orig = blockIdx.x;
  int bid = (orig&7)*136 + (orig>>3);
  int tileIdx = bid>>2, hg = bid&3;
  int si=0, t=tileIdx;
  #pragma unroll 1
  for(; si<32; si++){ int cnt=(si+2)>>1; if(t<cnt) break; t-=cnt; }
  int s0 = si*64, t0 = t*128;
  float* plane = (hg==0)?p0:(hg==1)?p1:(hg==2)?p2:p3;
  float* outp = plane + (size_t)tileIdx*8192;
  int h0 = hg*8;
  int tid=threadIdx.x, w=tid>>6, l=tid&63;
  int wm=w>>2, wn=w&3, l15=l&15, l16=l>>4;
  const float cscale = 0.015625f;
  #pragma unroll
  for(int rnd=0;rnd<4;rnd++){
    int cid = rnd*512 + w*64 + l;
    int row = cid>>4, cc = cid&15;
    int scc = cc ^ (row&7);
    GLDS(kih + (size_t)(t0+row)*128 + scc*8, Kh + rnd*4096 + w*512);
    GLDS(kil + (size_t)(t0+row)*128 + scc*8, Kl + rnd*4096 + w*512);
  }
  #pragma unroll
  for(int rnd=0;rnd<2;rnd++){
    int cid = rnd*512 + w*64 + l;
    int row = cid>>4, cc = cid&15;
    int scc = cc ^ (row&7);
    GLDS(qih + (size_t)(s0+row)*4096 + h0*128 + scc*8, Qb + rnd*4096 + w*512);
  }
  asm volatile("s_waitcnt vmcnt(0)" ::: "memory");
  __syncthreads();
  f32x4 accI[2][2], sc[2][2];
  #pragma unroll
  for(int m=0;m<2;m++) for(int n=0;n<2;n++) accI[m][n] = f32x4{0.f,0.f,0.f,0.f};
  for(int s=0;s<16;s++){
    const u16* Q = Qb;
    if((s&1)==0){
      #pragma unroll
      for(int m=0;m<2;m++) for(int n=0;n<2;n++) sc[m][n] = f32x4{0.f,0.f,0.f,0.f};
      isc_pass64(Q, Kh, sc, wm, wn, l15, l16);
      isc_pass64(Q, Kl, sc, wm, wn, l15, l16);
    } else {
      isc_pass64(Q, Kh, sc, wm, wn, l15, l16);
      int hh = h0 + (s>>1);
      #pragma unroll
      for(int m=0;m<2;m++)
        #pragma unroll
        for(int r=0;r<4;r++){
          float wv = wts[(size_t)(s0+wm*32+m*16+l16*4+r)*160 + 128 + hh]*cscale;
          #pragma unroll
          for(int n=0;n<2;n++) accI[m][n][r] += fmaxf(sc[m][n][r],0.f)*wv;
        }
    }
    __syncthreads();
    int nxt = s+1;
    if(nxt < 16){
      const u16* src = (nxt&1) ? qil : qih;
      int hh = h0 + (nxt>>1);
      #pragma unroll
      for(int rnd=0;rnd<2;rnd++){
        int cid = rnd*512 + w*64 + l;
        int row = cid>>4, cc = cid&15;
        int scc = cc ^ (row&7);
        GLDS(src + (size_t)(s0+row)*4096 + hh*128 + scc*8, Qb + rnd*4096 + w*512);
      }
      asm volatile("s_waitcnt vmcnt(0)" ::: "memory");
      __syncthreads();
    }
  }
  #pragma unroll
  for(int m=0;m<2;m++)
    #pragma unroll
    for(int n=0;n<2;n++)
      #pragma unroll
      for(int r=0;r<4;r++)
        outp[(wm*32+m*16+l16*4+r)*128 + wn*32 + n*16 + l15] = accI[m][n][r];
}

// ---------------- exact top-512 per row -> bitmask ----------------
DEV uint fkey(float f){ union{float f;uint u;} v; v.f=f; return (v.u & 0x80000000u) ? ~v.u : (v.u | 0x80000000u); }

__global__ __launch_bounds__(256) void topk_mask(
    const float* __restrict__ p0, const float* __restrict__ p1,
    const float* __restrict__ p2, const float* __restrict__ p3, u64* __restrict__ bits)
{
  int s = blockIdx.x;
  int n = s+1;
  int tid = threadIdx.x;
  if(n <= 512){
    for(int wI=tid; wI<32; wI+=256){
      u64 m=0; int base=wI*64;
      if(base < n){ int cnt=n-base; m = (cnt>=64)? ~0ull : ((1ull<<cnt)-1ull); }
      bits[(size_t)s*32+wI]=m;
    }
    return;
  }
  __shared__ float row[2048];
  __shared__ uint hist[256];
  __shared__ uint sh_B, sh_k;
  __shared__ uint wcnt[32];
  int si = s>>6, sr = s&63;
  size_t triBase = (size_t)(((si+1)*(si+1))>>2);
  for(int c=tid; c<n; c+=256){
    size_t off = (triBase + (size_t)(c>>7))*8192 + (size_t)sr*128 + (c&127);
    row[c] = p0[off]+p1[off]+p2[off]+p3[off];
  }
  __syncthreads();
  uint prefix=0, k=512;
  for(int shift=24; shift>=0; shift-=8){
    hist[tid]=0;
    __syncthreads();
    for(int t2=tid;t2<n;t2+=256){
      uint u = fkey(row[t2]);
      bool ok = (shift==24) || ((u>>(shift+8)) == (prefix>>(shift+8)));
      if(ok) atomicAdd(&hist[(u>>shift)&255u],1u);
    }
    __syncthreads();
    for(int offd=1; offd<256; offd<<=1){
      uint add = (tid+offd<256)? hist[tid+offd] : 0u;
      __syncthreads();
      hist[tid] += add;
      __syncthreads();
    }
    uint nxtv = (tid<255)? hist[tid+1] : 0u;
    if(hist[tid]>=k && nxtv<k){ sh_B=(uint)tid; sh_k = k - nxtv; }
    __syncthreads();
    prefix |= sh_B<<shift;
    k = sh_k;
    __syncthreads();
  }
  uint thr = prefix;
  if(tid<32) wcnt[tid]=0;
  __syncthreads();
  int nw = (n+63)>>6;
  if(tid < nw){
    int base=tid*64, end = base+64; if(end>n) end=n;
    uint c=0;
    for(int t2=base;t2<end;t2++) if(fkey(row[t2])==thr) c++;
    wcnt[tid]=c;
  }
  __syncthreads();
  if(tid==0){
    uint runv=0;
    for(int i=0;i<32;i++){ uint c=wcnt[i]; wcnt[i]=runv; runv+=c; }
  }
  __syncthreads();
  if(tid<32){
    u64 m=0; int base=tid*64;
    if(base<n){
      uint rank = wcnt[tid];
      int end = base+64; if(end>n) end=n;
      for(int t2=base;t2<end;t2++){
        uint u = fkey(row[t2]);
        if(u>thr) m |= (1ull<<(t2-base));
        else if(u==thr){ if(rank<k) m |= (1ull<<(t2-base)); rank++; }
      }
    }
    bits[(size_t)s*32+tid]=m;
  }
}

// ---------------- flash attention: no-max exp2 softmax, 3 blocks/CU ----------------
__global__ __launch_bounds__(256,3) void flash_attn(
    const u16* __restrict__ q, const u16* __restrict__ k, const u16* __restrict__ vt,
    const u64* __restrict__ bits, u16* __restrict__ o,
    u16* __restrict__ Opart, float* __restrict__ ml)
{
  __shared__ u16 Ks[64*192];
  __shared__ u16 Vt[128*64];
  __shared__ u16 Pl[64*72];
  int h = blockIdx.y;
  int pp = blockIdx.x;
  int sblk=0, chunk=0;
  for(int i=0;i<32;i++){
    int sb = 31-i; int ncc = (sb>>3)+1;
    if(pp < ncc){ sblk=sb; chunk=pp; break; }
    pp -= ncc;
  }
  int nc = (sblk>>3)+1, ntiles = sblk+1, s0 = sblk*64;
  int tid=threadIdx.x, w=tid>>6, l=tid&63;
  int l15=l&15, l16=l>>4;
  bf16x8 qf[6];
  #pragma unroll
  for(int ks=0;ks<6;ks++)
    qf[ks] = *reinterpret_cast<const bf16x8*>(&q[((size_t)(s0+w*16+l15)*16 + h)*192 + ks*32 + l16*8]);
  f32x4 Oa[8];
  #pragma unroll
  for(int n=0;n<8;n++) Oa[n] = f32x4{0.f,0.f,0.f,0.f};
  float lrun[4];
  #pragma unroll
  for(int r=0;r<4;r++) lrun[r]=0.f;
  int tt0 = chunk*8, tt1 = imin(tt0+8, ntiles);
  for(int tt=tt0; tt<tt1; tt++){
    int t0 = tt*64;
    __syncthreads();
    #pragma unroll
    for(int rnd=0;rnd<6;rnd++){
      int cid = rnd*256 + w*64 + l;
      int row = cid/24, cc = cid - row*24;
      int scc = cc ^ (row&7);
      GLDS(k + ((size_t)(t0+row)*16 + h)*192 + scc*8, Ks + rnd*2048 + w*512);
    }
    #pragma unroll
    for(int rnd=0;rnd<4;rnd++){
      int cid = rnd*256 + w*64 + l;
      int row = cid>>3, cc = cid&7;
      int scc = cc ^ (row&7);
      GLDS(vt + ((size_t)h*128 + row)*2048 + t0 + scc*8, Vt + rnd*2048 + w*512);
    }
    asm volatile("s_waitcnt vmcnt(0)" ::: "memory");
    __syncthreads();
    f32x4 S[4];
    #pragma unroll
    for(int n=0;n<4;n++) S[n] = f32x4{0.f,0.f,0.f,0.f};
    #pragma unroll
    for(int ks=0;ks<6;ks++){
      bf16x8 b[4];
      #pragma unroll
      for(int n=0;n<4;n++){
        int row = n*16+l15;
        b[n] = *reinterpret_cast<const bf16x8*>(&Ks[row*192 + ((((ks<<2)+l16) ^ (row&7))<<3)]);
      }
      #pragma unroll
      for(int n=0;n<4;n++) S[n] = MFMA(qf[ks], b[n], S[n]);
    }
    bool diag = (tt == sblk);
    #pragma unroll
    for(int r=0;r<4;r++){
      int srow = s0 + w*16 + l16*4 + r;
      u64 wrd = bits[(size_t)srow*32 + (t0>>6)];
      if(diag) wrd &= (((1ull<<(srow&63))<<1) - 1ull);
      float rs = 0.f;
      #pragma unroll
      for(int n=0;n<4;n++){
        int bitp = n*16 + l15;
        bool ok = (wrd>>bitp)&1ull;
        float p = ok ? exp2f(S[n][r]) : 0.f;
        S[n][r] = p;
        rs += p;
      }
      #pragma unroll
      for(int off=1;off<16;off<<=1) rs += __shfl_xor(rs, off, 64);
      lrun[r] += rs;
    }
    #pragma unroll
    for(int n=0;n<4;n++)
      #pragma unroll
      for(int r=0;r<4;r++)
        Pl[(w*16+l16*4+r)*72 + n*16+l15] = f2bf(S[n][r]);
    #pragma unroll
    for(int ks=0;ks<2;ks++){
      bf16x8 a = *reinterpret_cast<const bf16x8*>(&Pl[(w*16+l15)*72 + ks*32 + l16*8]);
      bf16x8 bb[8];
      #pragma unroll
      for(int n=0;n<8;n++){
        int d = n*16+l15;
        bb[n] = *reinterpret_cast<const bf16x8*>(&Vt[d*64 + ((((ks<<2)+l16) ^ (d&7))<<3)]);
      }
      #pragma unroll
      for(int n=0;n<8;n++) Oa[n] = MFMA(a, bb[n], Oa[n]);
    }
  }
  if(nc == 1){
    #pragma unroll
    for(int r=0;r<4;r++){
      int srow = s0 + w*16 + l16*4 + r;
      float inv = 1.f/lrun[r];
      #pragma unroll
      for(int n=0;n<8;n++)
        o[(size_t)srow*2048 + h*128 + n*16 + l15] = f2bf(Oa[n][r]*inv);
    }
  } else {
    int part = ((h*32 + sblk)<<2) + chunk;
    u16* Op = Opart + (size_t)part*8192;
    #pragma unroll
    for(int r=0;r<4;r++){
      int rit = w*16 + l16*4 + r;
      #pragma unroll
      for(int n=0;n<8;n++)
        Op[rit*128 + n*16 + l15] = f2bf(Oa[n][r]);
      if(l15==0)
        ml[(size_t)part*128 + rit*2+1] = lrun[r];
    }
  }
}

__global__ __launch_bounds__(256) void flash_combine(
    const u16* __restrict__ Opart, const float* __restrict__ ml, u16* __restrict__ o)
{
  int b = blockIdx.x;
  int h = b/24, sblk = 8 + (b%24);
  int nc = (sblk>>3)+1;
  int tid = threadIdx.x;
  int r = tid>>2, dq = (tid&3)*32;
  int s0 = sblk*64;
  int pbase = (h*32+sblk)<<2;
  float L = 0.f;
  for(int c=0;c<nc;c++) L += ml[(size_t)(pbase+c)*128 + r*2 + 1];
  float inv = 1.f/L;
  for(int dd=0; dd<32; dd+=8){
    float accv[8];
    #pragma unroll
    for(int j=0;j<8;j++) accv[j]=0.f;
    for(int c=0;c<nc;c++){
      u16x8 pv = *reinterpret_cast<const u16x8*>(&Opart[(size_t)(pbase+c)*8192 + r*128 + dq + dd]);
      #pragma unroll
      for(int j=0;j<8;j++) accv[j] += bf2f(pv[j]);
    }
    u16x8 ov;
    #pragma unroll
    for(int j=0;j<8;j++) ov[j] = f2bf(accv[j]*inv);
    *reinterpret_cast<u16x8*>(&o[(size_t)(s0+r)*2048 + h*128 + dq + dd]) = ov;
  }
}

// ---------------- host ----------------
extern "C" void kernel_launch(void* const* d_in, const int* in_sizes, int n_in,
                              void* d_out, int out_size, void* d_ws, size_t ws_size,
                              hipStream_t stream)
{
  (void)in_sizes; (void)n_in; (void)out_size;
  const float* hs   = (const float*)d_in[0];
  const float* wqa  = (const float*)d_in[1];
  const float* qnw  = (const float*)d_in[2];
  const float* wqbw = (const float*)d_in[3];
  const float* wkva = (const float*)d_in[4];
  const float* kvnw = (const float*)d_in[5];
  const float* wkvb = (const float*)d_in[6];
  const float* wow  = (const float*)d_in[7];
  const float* iwqb = (const float*)d_in[8];
  const float* iwk  = (const float*)d_in[9];
  const float* iknw = (const float*)d_in[10];
  const float* iknb = (const float*)d_in[11];
  const float* iwp  = (const float*)d_in[12];
  const float* fcos = (const float*)d_in[13];
  const float* fsin = (const float*)d_in[14];
  float* outp = (float*)d_out;

  char* base = (char*)d_ws;
  size_t off = 0;
  auto alloc = [&](size_t bytes)->char*{ char* p = base+off; off += (bytes+255)&~(size_t)255; return p; };
  u16* hid_hi = (u16*)alloc(2048ull*2048*2);
  u16* hid_lo = (u16*)alloc(2048ull*2048*2);
  u16* wqa_hi = (u16*)alloc(1536ull*2048*2);
  u16* wqa_lo = (u16*)alloc(1536ull*2048*2);
  u16* wqb_b  = (u16*)alloc(3072ull*1536*2);
  u16* wkva_b = (u16*)alloc(576ull*2048*2);
  u16* wkvb_b = (u16*)alloc(4096ull*512*2);
  u16* wo_b   = (u16*)alloc(2048ull*2048*2);
  u16* iwqb_hi= (u16*)alloc(4096ull*1536*2);
  u16* iwqb_lo= (u16*)alloc(4096ull*1536*2);
  u16* kiwp_hi= (u16*)alloc(160ull*2048*2);
  u16* kiwp_lo= (u16*)alloc(160ull*2048*2);
  float* kiwp_C=(float*)alloc(2048ull*160*4);
  u16* qr_hi  = (u16*)alloc(2048ull*1536*2);
  u16* qr_lo  = (u16*)alloc(2048ull*1536*2);
  u16* kv_b   = (u16*)alloc(2048ull*512*2);
  float* kpe  = (float*)alloc(2048ull*64*4);
  u16* k_b    = (u16*)alloc(2048ull*16*192*2);
  u16* v_t    = (u16*)alloc(16ull*128*2048*2);
  u16* ki_hi  = (u16*)alloc(2048ull*128*2);
  u16* ki_lo  = (u16*)alloc(2048ull*128*2);
  u64* bits   = (u64*)alloc(2048ull*32*8);
  u16* attn_b = (u16*)alloc(2048ull*2048*2);
  float* reg1 = (float*)alloc(2048ull*4096*4);
  if(ws_size < off) return;

  // aliases (lifetime-checked)
  u16* q_b      = wqa_hi;            // spans wqa_hi+wqa_lo; wq_a dead after qr gemm; written by q-GEMM EPI=1
  u16* qi_hi    = hid_hi;            // spans hid_hi+hid_lo; hidden dead after kiwp gemm
  u16* qi_lo    = iwqb_hi;           // spans into iwqb_lo; idx_wq_b dead after qi gemm
  float* ml     = (float*)qr_lo;     // qr dead after qi gemm
  float* qr_pre = reg1;
  float* kva_part = reg1;
  float* kvp    = reg1;
  float* kiwp_part = reg1;
  float* qi_pre = reg1;
  const size_t PLANE = 272ull*8192;
  float* ip0 = reg1;
  float* ip1 = reg1 + PLANE;
  float* ip2 = reg1 + 2*PLANE;
  float* ip3 = (float*)wqb_b;        // wqb_b dead after q gemm
  u16* Opart = (u16*)reg1;

  auto G1 = [&](const u16* A,int lda,const u16* B,int ldb,float* C,int ldc,int M,int N,int K,int z){
    dim3 g((unsigned)((N+127)/128), (unsigned)((M+127)/128), (unsigned)z);
    gemm_glds<0,64,0><<<g,256,0,stream>>>(A,nullptr,lda,B,nullptr,ldb,C,ldc,M,N,K,nullptr,nullptr,nullptr);
  };
  auto G3 = [&](const u16* Ah,const u16* Al,int lda,const u16* Bh,const u16* Bl,int ldb,float* C,int ldc,int M,int N,int K,int z){
    dim3 g((unsigned)((N+127)/128), (unsigned)((M+127)/128), (unsigned)z);
    gemm_glds<1,64,0><<<g,256,0,stream>>>(Ah,Al,lda,Bh,Bl,ldb,C,ldc,M,N,K,nullptr,nullptr,nullptr);
  };

  cvt_all<<<2048,256,0,stream>>>(hs,wqa,iwqb,iwk,iwp,wqbw,wkva,wkvb,wow,
      hid_hi,hid_lo,wqa_hi,wqa_lo,iwqb_hi,iwqb_lo,kiwp_hi,kiwp_lo,
      wqb_b,wkva_b,wkvb_b,wo_b);

  // qr = rmsnorm(hidden @ wq_a^T), split-K z=2, plane-sum fused into rmsnorm
  G3(hid_hi,hid_lo,2048, wqa_hi,wqa_lo,2048, qr_pre,1536, 2048,1536,2048, 2);
  rmsnorm_qr_split<<<2048,256,0,stream>>>(qr_pre, qnw, qr_hi, qr_lo);

  // q path: GEMM with fused rope+scale+bf16 epilogue (writes q_b directly)
  {
    dim3 g(24, 16, 1);
    gemm_glds<0,64,1><<<g,256,0,stream>>>(qr_hi,nullptr,1536, wqb_b,nullptr,1536,
        nullptr,0, 2048,3072,1536, q_b, fcos, fsin);
  }

  // kv path (split-K z=4, plane-sum fused into kv_norm_rope)
  G1(hid_hi,2048, wkva_b,2048, kva_part,576, 2048,576,2048, 4);
  kv_norm_rope<<<2048,256,0,stream>>>(kva_part, kvnw, fcos, fsin, kv_b, kpe);
  G1(kv_b,512, wkvb_b,512, kvp,4096, 2048,4096,512, 1);
  transpose_assemble<<<dim3(32,16),256,0,stream>>>(kvp, kpe, v_t, k_b);

  // indexer ki + wts packed (N=160, split-K z=8)
  G3(hid_hi,hid_lo,2048, kiwp_hi,kiwp_lo,2048, kiwp_part,160, 2048,160,2048, 8);
  ki_ln_rope_split<<<2048,128,0,stream>>>(kiwp_part, iknw, iknb, fcos, fsin, ki_hi, ki_lo, kiwp_C);

  // indexer qi
  G3(qr_hi,qr_lo,1536, iwqb_hi,iwqb_lo,1536, qi_pre,4096, 2048,4096,1536, 1);
  qi_rope_split<<<2048,256,0,stream>>>(qi_pre, fcos, fsin, qi_hi, qi_lo);

  // fused index scores + topk
  idx_scores7<<<1088,512,0,stream>>>(qi_hi, qi_lo, ki_hi, ki_lo, kiwp_C, ip0, ip1, ip2, ip3);
  topk_mask<<<2048,256,0,stream>>>(ip0, ip1, ip2, ip3, bits);

  // attention + combine + output projection
  flash_attn<<<dim3(80,16),256,0,stream>>>(q_b, k_b, v_t, bits, attn_b, Opart, ml);
  flash_combine<<<384,256,0,stream>>>(Opart, ml, attn_b);
  G1(attn_b,2048, wo_b,2048, outp,2048, 2048,2048,2048, 1);
}

// Round 22
// 473.734 us; speedup vs baseline: 1.0134x; 1.0071x over previous
//
#include <hip/hip_runtime.h>
#include <stdint.h>

typedef unsigned int uint;
typedef unsigned short u16;
typedef unsigned long long u64;

typedef float  f32x4 __attribute__((ext_vector_type(4)));
typedef uint   u32x4 __attribute__((ext_vector_type(4)));
typedef u16    u16x4 __attribute__((ext_vector_type(4)));
typedef u16    u16x8 __attribute__((ext_vector_type(8)));
typedef __bf16 bf16x8 __attribute__((ext_vector_type(8)));

#define DEV static __device__ __forceinline__
#define MFMA(a,b,c) __builtin_amdgcn_mfma_f32_16x16x32_bf16((a),(b),(c),0,0,0)
#define GLDS(src,dst) __builtin_amdgcn_global_load_lds((const __attribute__((address_space(1))) void*)(src),(__attribute__((address_space(3))) void*)(dst),16,0,0)

DEV u16 f2bf(float x){ union{float f;uint u;} v; v.f=x; return (u16)((v.u + 0x7fffu + ((v.u>>16)&1u))>>16); }
DEV float bf2f(u16 b){ union{uint u;float f;} v; v.u=((uint)b)<<16; return v.f; }
DEV int imin(int a,int b){ return a<b?a:b; }

// ---------------- fused converts ----------------
__global__ void cvt_all(
    const float* __restrict__ hs, const float* __restrict__ wqa, const float* __restrict__ iwqb,
    const float* __restrict__ iwk, const float* __restrict__ iwp,
    const float* __restrict__ wqbw, const float* __restrict__ wkva, const float* __restrict__ wkvb,
    const float* __restrict__ wow,
    u16* __restrict__ hid_hi, u16* __restrict__ hid_lo, u16* __restrict__ wqa_hi, u16* __restrict__ wqa_lo,
    u16* __restrict__ iwqb_hi, u16* __restrict__ iwqb_lo, u16* __restrict__ kiwp_hi, u16* __restrict__ kiwp_lo,
    u16* __restrict__ wqb_b, u16* __restrict__ wkva_b, u16* __restrict__ wkvb_b, u16* __restrict__ wo_b)
{
  int i = blockIdx.x*blockDim.x + threadIdx.x;
  int st = gridDim.x*blockDim.x;
  for(; i < 6537216; i += st){
    const float* src; u16 *dh, *dl=nullptr; int j; bool split;
    if(i < 1048576){ src=hs;   dh=hid_hi;  dl=hid_lo;  j=i;         split=true; }
    else if(i < 1835008){ src=wqa;  dh=wqa_hi;  dl=wqa_lo;  j=i-1048576; split=true; }
    else if(i < 3407872){ src=iwqb; dh=iwqb_hi; dl=iwqb_lo; j=i-1835008; split=true; }
    else if(i < 3473408){ src=iwk;  dh=kiwp_hi; dl=kiwp_lo; j=i-3407872; split=true; }
    else if(i < 3489792){ src=iwp;  dh=kiwp_hi+128*2048; dl=kiwp_lo+128*2048; j=i-3473408; split=true; }
    else if(i < 4669440){ src=wqbw; dh=wqb_b;  j=i-3489792; split=false; }
    else if(i < 4964352){ src=wkva; dh=wkva_b; j=i-4669440; split=false; }
    else if(i < 5488640){ src=wkvb; dh=wkvb_b; j=i-4964352; split=false; }
    else               { src=wow;  dh=wo_b;   j=i-5488640; split=false; }
    f32x4 x = reinterpret_cast<const f32x4*>(src)[j];
    u16x4 h;
    #pragma unroll
    for(int k=0;k<4;k++) h[k]=f2bf(x[k]);
    reinterpret_cast<u16x4*>(dh)[j]=h;
    if(split){
      u16x4 l;
      #pragma unroll
      for(int k=0;k<4;k++) l[k]=f2bf(x[k]-bf2f(h[k]));
      reinterpret_cast<u16x4*>(dl)[j]=l;
    }
  }
}

// ---------------- GEMM (glds staging + T2 XOR swizzle, m97 structure) ----------------
template<int BK>
DEV void stageT(const u16* __restrict__ gbase, int ld, int row0, int maxrow, int k0, u16* lds){
  int tid = threadIdx.x, w = tid>>6, l = tid&63;
  if(BK==32){
    #pragma unroll
    for(int j=0;j<2;j++){
      int seg = w + j*4;
      int row = seg*16 + (l>>2);
      int gr = row0 + row; if(gr > maxrow) gr = maxrow;
      int u = (l&3) ^ ((l>>2)&3);
      GLDS(gbase + (size_t)gr*ld + k0 + u*8, lds + seg*512);
    }
  } else { // BK==64
    #pragma unroll
    for(int j=0;j<4;j++){
      int c = w + j*4;
      int row = c*8 + (l>>3);
      int gr = row0 + row; if(gr > maxrow) gr = maxrow;
      int u = (l&7) ^ ((l>>3)&7);
      GLDS(gbase + (size_t)gr*ld + k0 + u*8, lds + c*512);
    }
  }
}

template<int SPLIT, int BK, int EPI>
__global__ __launch_bounds__(256,2) void gemm_glds(
    const u16* __restrict__ Ah, const u16* __restrict__ Al, int lda,
    const u16* __restrict__ Bh, const u16* __restrict__ Bl, int ldb,
    float* __restrict__ C, int ldc, int M, int N, int K,
    u16* __restrict__ O1, const float* __restrict__ fcos, const float* __restrict__ fsin)
{
  __shared__ u16 sAh[128*BK];
  __shared__ u16 sBh[128*BK];
  __shared__ u16 sAl[SPLIT?128*BK:8];
  __shared__ u16 sBl[SPLIT?128*BK:8];
  const int tid = threadIdx.x;
  const int w = tid>>6, l = tid&63;
  const int wr = w>>1, wc = w&1;
  const int l15 = l&15, l16 = l>>4;
  const int UM = BK/8 - 1;

  int gx = gridDim.x;
  int nwg = gx*gridDim.y;
  int orig = blockIdx.x + gx*blockIdx.y;
  int qq = nwg>>3, rr = nwg&7, xc = orig&7, oo = orig>>3;
  int wg = (xc<rr ? xc*(qq+1) : rr*(qq+1)+(xc-rr)*qq) + oo;
  int m0 = (wg/gx)*128, n0 = (wg%gx)*128;

  int kz = K/(int)gridDim.z;
  int kbeg = blockIdx.z*kz;

  f32x4 acc[4][4];
  #pragma unroll
  for(int m=0;m<4;m++)
    #pragma unroll
    for(int n=0;n<4;n++) acc[m][n] = f32x4{0.f,0.f,0.f,0.f};

  for(int k0=kbeg; k0<kbeg+kz; k0+=BK){
    __syncthreads();
    stageT<BK>(Ah, lda, m0, M-1, k0, sAh);
    stageT<BK>(Bh, ldb, n0, N-1, k0, sBh);
    if(SPLIT){
      stageT<BK>(Al, lda, m0, M-1, k0, sAl);
      stageT<BK>(Bl, ldb, n0, N-1, k0, sBl);
    }
    asm volatile("s_waitcnt vmcnt(0)" ::: "memory");
    __syncthreads();
    #pragma unroll
    for(int kk=0;kk<BK/32;kk++){
      bf16x8 ah[4], bh[4];
      #pragma unroll
      for(int m=0;m<4;m++){
        int row = wr*64+m*16+l15;
        ah[m] = *reinterpret_cast<const bf16x8*>(&sAh[row*BK + ((kk*4+l16)^(row&UM))*8]);
      }
      #pragma unroll
      for(int n=0;n<4;n++){
        int row = wc*64+n*16+l15;
        bh[n] = *reinterpret_cast<const bf16x8*>(&sBh[row*BK + ((kk*4+l16)^(row&UM))*8]);
      }
      #pragma unroll
      for(int m=0;m<4;m++)
        #pragma unroll
        for(int n=0;n<4;n++) acc[m][n] = MFMA(ah[m], bh[n], acc[m][n]);
      if(SPLIT){
        bf16x8 t[4];
        #pragma unroll
        for(int n=0;n<4;n++){
          int row = wc*64+n*16+l15;
          t[n] = *reinterpret_cast<const bf16x8*>(&sBl[row*BK + ((kk*4+l16)^(row&UM))*8]);
        }
        #pragma unroll
        for(int m=0;m<4;m++)
          #pragma unroll
          for(int n=0;n<4;n++) acc[m][n] = MFMA(ah[m], t[n], acc[m][n]);
        #pragma unroll
        for(int m=0;m<4;m++){
          int row = wr*64+m*16+l15;
          t[m] = *reinterpret_cast<const bf16x8*>(&sAl[row*BK + ((kk*4+l16)^(row&UM))*8]);
        }
        #pragma unroll
        for(int m=0;m<4;m++)
          #pragma unroll
          for(int n=0;n<4;n++) acc[m][n] = MFMA(t[m], bh[n], acc[m][n]);
      }
    }
  }
  if(EPI==0){
    float* Cp = C + (size_t)blockIdx.z*M*ldc;
    #pragma unroll
    for(int m=0;m<4;m++){
      int row = m0 + wr*64 + m*16 + l16*4;
      #pragma unroll
      for(int n=0;n<4;n++){
        int col = n0 + wc*64 + n*16 + l15;
        if(col < N){
          #pragma unroll
          for(int r=0;r<4;r++){
            int rrow = row + r;
            if(rrow < M) Cp[(size_t)rrow*ldc + col] = acc[m][n][r];
          }
        }
      }
    }
  } else {
    // EPI==1: fused q-rope (interleaved pairs = xor-adjacent lanes) + scale + bf16
    const float qsc = 0.10411756f;   // log2(e)/sqrt(192)
    #pragma unroll
    for(int m=0;m<4;m++){
      int rowb = m0 + wr*64 + m*16 + l16*4;
      #pragma unroll
      for(int n=0;n<4;n++){
        int col = n0 + wc*64 + n*16 + l15;
        int hq = col/192;
        int d  = col - hq*192;
        #pragma unroll
        for(int r=0;r<4;r++){
          int row = rowb + r;
          float v = acc[m][n][r];
          float p = __shfl_xor(v, 1, 64);   // pair partner (co-active: d parity == lane parity)
          float vv;
          if(d < 128) vv = v;
          else{
            int i2 = (d-128)>>1;
            float c0 = fcos[row*32 + i2], s_ = fsin[row*32 + i2];
            vv = ((d&1)==0) ? (v*c0 - p*s_) : (p*s_ + v*c0);
          }
          O1[(size_t)row*3072 + col] = f2bf(vv*qsc);
        }
      }
    }
  }
}

// ---------------- norms / rope ----------------
__global__ __launch_bounds__(256) void rmsnorm_qr_split(
    const float* __restrict__ in, const float* __restrict__ w,
    u16* __restrict__ hi, u16* __restrict__ lo)
{
  int s = blockIdx.x, tid = threadIdx.x;
  __shared__ float red[4];
  const float* x = in + (size_t)s*1536;
  const size_t plane = 2048ull*1536;
  float xv[6]; float ss=0.f;
  #pragma unroll
  for(int i=0;i<6;i++){ int c = tid+i*256; xv[i] = x[c] + x[plane+c]; ss += xv[i]*xv[i]; }
  #pragma unroll
  for(int o=32;o>0;o>>=1) ss += __shfl_down(ss,o,64);
  if((tid&63)==0) red[tid>>6]=ss;
  __syncthreads();
  float total = red[0]+red[1]+red[2]+red[3];
  float scale = rsqrtf(total*(1.0f/1536.0f) + 1e-6f);
  #pragma unroll
  for(int i=0;i<6;i++){
    int c = tid + i*256;
    float vv = xv[i]*scale*w[c];
    u16 hv = f2bf(vv);
    hi[(size_t)s*1536+c]=hv;
    lo[(size_t)s*1536+c]=f2bf(vv - bf2f(hv));
  }
}

__global__ __launch_bounds__(256) void kv_norm_rope(
    const float* __restrict__ kva, const float* __restrict__ w,
    const float* __restrict__ fcos, const float* __restrict__ fsin,
    u16* __restrict__ kvb, float* __restrict__ kpe)
{
  int s = blockIdx.x, tid = threadIdx.x;
  __shared__ float red[4];
  const size_t plane = 2048ull*576;
  float xv[2]={0.f,0.f};
  #pragma unroll
  for(int c=0;c<4;c++){
    const float* xp = kva + (size_t)c*plane + (size_t)s*576;
    xv[0]+=xp[tid]; xv[1]+=xp[tid+256];
  }
  float ss = xv[0]*xv[0]+xv[1]*xv[1];
  #pragma unroll
  for(int o=32;o>0;o>>=1) ss += __shfl_down(ss,o,64);
  if((tid&63)==0) red[tid>>6]=ss;
  __syncthreads();
  float total = red[0]+red[1]+red[2]+red[3];
  float scale = rsqrtf(total*(1.0f/512.0f)+1e-6f);
  #pragma unroll
  for(int i=0;i<2;i++){ int c=tid+i*256; kvb[(size_t)s*512+c]=f2bf(xv[i]*scale*w[c]); }
  if(tid<32){
    float x0=0.f, x1=0.f;
    #pragma unroll
    for(int c=0;c<4;c++){
      const float* xp = kva + (size_t)c*plane + (size_t)s*576;
      x0 += xp[512+2*tid]; x1 += xp[513+2*tid];
    }
    float c0=fcos[(size_t)s*32+tid], s_=fsin[(size_t)s*32+tid];
    kpe[(size_t)s*64+2*tid]   = x0*c0 - x1*s_;
    kpe[(size_t)s*64+2*tid+1] = x0*s_ + x1*c0;
  }
}

__global__ __launch_bounds__(256) void qi_rope_split(const float* __restrict__ qpre,
    const float* __restrict__ fcos, const float* __restrict__ fsin,
    u16* __restrict__ hi, u16* __restrict__ lo)
{
  int s = blockIdx.x;
  const float* rowp = qpre + (size_t)s*4096;
  for(int idx=threadIdx.x; idx<4096; idx+=256){
    int hh = idx>>7, d = idx&127;
    const float* hb = rowp + (hh<<7);
    float vv;
    if(d<32){ float c0=fcos[(size_t)s*32+d], s_=fsin[(size_t)s*32+d]; vv = hb[d]*c0 - hb[d+32]*s_; }
    else if(d<64){ int i2=d-32; float c0=fcos[(size_t)s*32+i2], s_=fsin[(size_t)s*32+i2]; vv = hb[i2]*s_ + hb[d]*c0; }
    else vv = hb[d];
    u16 hv = f2bf(vv);
    hi[(size_t)s*4096+idx]=hv;
    lo[(size_t)s*4096+idx]=f2bf(vv - bf2f(hv));
  }
}

__global__ __launch_bounds__(128) void ki_ln_rope_split(
    const float* __restrict__ kpre, const float* __restrict__ w, const float* __restrict__ bb,
    const float* __restrict__ fcos, const float* __restrict__ fsin,
    u16* __restrict__ hi, u16* __restrict__ lo, float* __restrict__ wts_out)
{
  int s = blockIdx.x, tid = threadIdx.x;
  __shared__ float red[2];
  __shared__ float ybuf[128];
  const size_t plane = 2048ull*160;
  float x = 0.f;
  #pragma unroll
  for(int c=0;c<8;c++) x += kpre[(size_t)c*plane + (size_t)s*160 + tid];
  if(tid<32){
    float ws = 0.f;
    #pragma unroll
    for(int c=0;c<8;c++) ws += kpre[(size_t)c*plane + (size_t)s*160 + 128 + tid];
    wts_out[(size_t)s*160 + 128 + tid] = ws;
  }
  float v = x;
  #pragma unroll
  for(int o=32;o>0;o>>=1) v += __shfl_down(v,o,64);
  if((tid&63)==0) red[tid>>6]=v;
  __syncthreads();
  float mean = (red[0]+red[1])*(1.f/128.f);
  __syncthreads();
  float dx = x - mean;
  v = dx*dx;
  #pragma unroll
  for(int o=32;o>0;o>>=1) v += __shfl_down(v,o,64);
  if((tid&63)==0) red[tid>>6]=v;
  __syncthreads();
  float var = (red[0]+red[1])*(1.f/128.f);
  float y = dx*rsqrtf(var+1e-5f)*w[tid] + bb[tid];
  ybuf[tid]=y;
  __syncthreads();
  float r;
  if(tid<32){ float c0=fcos[(size_t)s*32+tid], s_=fsin[(size_t)s*32+tid]; r = ybuf[tid]*c0 - ybuf[tid+32]*s_; }
  else if(tid<64){ int i2=tid-32; float c0=fcos[(size_t)s*32+i2], s_=fsin[(size_t)s*32+i2]; r = ybuf[i2]*s_ + ybuf[tid]*c0; }
  else r = y;
  u16 hv=f2bf(r);
  hi[(size_t)s*128+tid]=hv;
  lo[(size_t)s*128+tid]=f2bf(r-bf2f(hv));
}

// transpose V + assemble K in one kernel. grid (32, 16)
__global__ __launch_bounds__(256) void transpose_assemble(const float* __restrict__ kvp,
    const float* __restrict__ kpe, u16* __restrict__ vt, u16* __restrict__ kb){
  __shared__ u16 T[64*136];
  int s0 = blockIdx.x*64, h = blockIdx.y;
  int tid = threadIdx.x;
  for(int idx=tid; idx<64*192; idx+=256){
    int r = idx/192, d = idx - r*192;
    float val = (d<128) ? kvp[(size_t)(s0+r)*4096 + h*256 + d] : kpe[(size_t)(s0+r)*64 + (d-128)];
    kb[((size_t)(s0+r)*16 + h)*192 + d] = f2bf(val);
  }
  #pragma unroll
  for(int i=0;i<8;i++){
    int ch = i*256 + tid;
    int r = ch>>5, cc = ch&31;
    f32x4 x = *reinterpret_cast<const f32x4*>(&kvp[(size_t)(s0+r)*4096 + h*256 + 128 + cc*4]);
    u16x4 y;
    #pragma unroll
    for(int j=0;j<4;j++) y[j] = f2bf(x[j]);
    *reinterpret_cast<u16x4*>(&T[r*136 + cc*4]) = y;
  }
  __syncthreads();
  #pragma unroll
  for(int i=0;i<4;i++){
    int ch = i*256 + tid;
    int d = ch>>3, sc = ch&7;
    u16x8 y;
    #pragma unroll
    for(int j=0;j<8;j++) y[j] = T[(sc*8+j)*136 + d];
    *reinterpret_cast<u16x8*>(&vt[((size_t)h*128 + d)*2048 + s0 + sc*8]) = y;
  }
}

// ---------------- fused indexer scores v8 (best: 82us) ----------------
DEV void isc_pass64(const u16* __restrict__ Q, const u16* __restrict__ Kb,
                    f32x4 (&sc)[2][2], int wm, int wn, int l15, int l16){
  #pragma unroll
  for(int ks=0;ks<4;ks++){
    bf16x8 a[2], b[2];
    #pragma unroll
    for(int m=0;m<2;m++){
      int row = wm*32 + m*16 + l15;
      a[m] = *reinterpret_cast<const bf16x8*>(&Q[row*128 + ((((ks<<2)+l16) ^ (row&7))<<3)]);
    }
    #pragma unroll
    for(int n=0;n<2;n++){
      int row = wn*32 + n*16 + l15;
      b[n] = *reinterpret_cast<const bf16x8*>(&Kb[row*128 + ((((ks<<2)+l16) ^ (row&7))<<3)]);
    }
    #pragma unroll
    for(int m=0;m<2;m++)
      #pragma unroll
      for(int n=0;n<2;n++) sc[m][n] = MFMA(a[m], b[n], sc[m][n]);
  }
}

__global__ __launch_bounds__(512,4) void idx_scores7(
    const u16* __restrict__ qih, const u16* __restrict__ qil,
    const u16* __restrict__ kih, const u16* __restrict__ kil,
    const float* __restrict__ wts,
    float* __restrict__ p0, float* __restrict__ p1, float* __restrict__ p2, float* __restrict__ p3)
{
  __shared__ u16 Kh[128*128];
  __shared__ u16 Kl[128*128];
  __shared__ u16 Qb[64*128];
  int orig = blockIdx.x;
  int bid = (orig&7)*136 + (orig>>3);
  int tileIdx = bid>>2, hg = bid&3;
  int si=0, t=tileIdx;
  #pragma unroll 1
  for(; si<32; si++){ int cnt=(si+2)>>1; if(t<cnt) break; t-=cnt; }
  int s0 = si*64, t0 = t*128;
  float* plane = (hg==0)?p0:(hg==1)?p1:(hg==2)?p2:p3;
  float* outp = plane + (size_t)tileIdx*8192;
  int h0 = hg*8;
  int tid=threadIdx.x, w=tid>>6, l=tid&63;
  int wm=w>>2, wn=w&3, l15=l&15, l16=l>>4;
  const float cscale = 0.015625f;
  #pragma unroll
  for(int rnd=0;rnd<4;rnd++){
    int cid = rnd*512 + w*64 + l;
    int row = cid>>4, cc = cid&15;
    int scc = cc ^ (row&7);
    GLDS(kih + (size_t)(t0+row)*128 + scc*8, Kh + rnd*4096 + w*512);
    GLDS(kil + (size_t)(t0+row)*128 + scc*8, Kl + rnd*4096 + w*512);
  }
  #pragma unroll
  for(int rnd=0;rnd<2;rnd++){
    int cid = rnd*512 + w*64 + l;
    int row = cid>>4, cc = cid&15;
    int scc = cc ^ (row&7);
    GLDS(qih + (size_t)(s0+row)*4096 + h0*128 + scc*8, Qb + rnd*4096 + w*512);
  }
  asm volatile("s_waitcnt vmcnt(0)" ::: "memory");
  __syncthreads();
  f32x4 accI[2][2], sc[2][2];
  #pragma unroll
  for(int m=0;m<2;m++) for(int n=0;n<2;n++) accI[m][n] = f32x4{0.f,0.f,0.f,0.f};
  for(int s=0;s<16;s++){
    const u16* Q = Qb;
    if((s&1)==0){
      #pragma unroll
      for(int m=0;m<2;m++) for(int n=0;n<2;n++) sc[m][n] = f32x4{0.f,0.f,0.f,0.f};
      isc_pass64(Q, Kh, sc, wm, wn, l15, l16);
      isc_pass64(Q, Kl, sc, wm, wn, l15, l16);
    } else {
      isc_pass64(Q, Kh, sc, wm, wn, l15, l16);
      int hh = h0 + (s>>1);
      #pragma unroll
      for(int m=0;m<2;m++)
        #pragma unroll
        for(int r=0;r<4;r++){
          float wv = wts[(size_t)(s0+wm*32+m*16+l16*4+r)*160 + 128 + hh]*cscale;
          #pragma unroll
          for(int n=0;n<2;n++) accI[m][n][r] += fmaxf(sc[m][n][r],0.f)*wv;
        }
    }
    __syncthreads();
    int nxt = s+1;
    if(nxt < 16){
      const u16* src = (nxt&1) ? qil : qih;
      int hh = h0 + (nxt>>1);
      #pragma unroll
      for(int rnd=0;rnd<2;rnd++){
        int cid = rnd*512 + w*64 + l;
        int row = cid>>4, cc = cid&15;
        int scc = cc ^ (row&7);
        GLDS(src + (size_t)(s0+row)*4096 + hh*128 + scc*8, Qb + rnd*4096 + w*512);
      }
      asm volatile("s_waitcnt vmcnt(0)" ::: "memory");
      __syncthreads();
    }
  }
  #pragma unroll
  for(int m=0;m<2;m++)
    #pragma unroll
    for(int n=0;n<2;n++)
      #pragma unroll
      for(int r=0;r<4;r++)
        outp[(wm*32+m*16+l16*4+r)*128 + wn*32 + n*16 + l15] = accI[m][n][r];
}

// ---------------- exact top-512 per row -> bitmask ----------------
DEV uint fkey(float f){ union{float f;uint u;} v; v.f=f; return (v.u & 0x80000000u) ? ~v.u : (v.u | 0x80000000u); }

__global__ __launch_bounds__(256) void topk_mask(
    const float* __restrict__ p0, const float* __restrict__ p1,
    const float* __restrict__ p2, const float* __restrict__ p3, u64* __restrict__ bits)
{
  int s = blockIdx.x;
  int n = s+1;
  int tid = threadIdx.x;
  if(n <= 512){
    for(int wI=tid; wI<32; wI+=256){
      u64 m=0; int base=wI*64;
      if(base < n){ int cnt=n-base; m = (cnt>=64)? ~0ull : ((1ull<<cnt)-1ull); }
      bits[(size_t)s*32+wI]=m;
    }
    return;
  }
  __shared__ float row[2048];
  __shared__ uint hist[256];
  __shared__ uint sh_B, sh_k;
  __shared__ uint wcnt[32];
  int si = s>>6, sr = s&63;
  size_t triBase = (size_t)(((si+1)*(si+1))>>2);
  for(int c=tid; c<n; c+=256){
    size_t off = (triBase + (size_t)(c>>7))*8192 + (size_t)sr*128 + (c&127);
    row[c] = p0[off]+p1[off]+p2[off]+p3[off];
  }
  __syncthreads();
  uint prefix=0, k=512;
  for(int shift=24; shift>=0; shift-=8){
    hist[tid]=0;
    __syncthreads();
    for(int t2=tid;t2<n;t2+=256){
      uint u = fkey(row[t2]);
      bool ok = (shift==24) || ((u>>(shift+8)) == (prefix>>(shift+8)));
      if(ok) atomicAdd(&hist[(u>>shift)&255u],1u);
    }
    __syncthreads();
    for(int offd=1; offd<256; offd<<=1){
      uint add = (tid+offd<256)? hist[tid+offd] : 0u;
      __syncthreads();
      hist[tid] += add;
      __syncthreads();
    }
    uint nxtv = (tid<255)? hist[tid+1] : 0u;
    if(hist[tid]>=k && nxtv<k){ sh_B=(uint)tid; sh_k = k - nxtv; }
    __syncthreads();
    prefix |= sh_B<<shift;
    k = sh_k;
    __syncthreads();
  }
  uint thr = prefix;
  if(tid<32) wcnt[tid]=0;
  __syncthreads();
  int nw = (n+63)>>6;
  if(tid < nw){
    int base=tid*64, end = base+64; if(end>n) end=n;
    uint c=0;
    for(int t2=base;t2<end;t2++) if(fkey(row[t2])==thr) c++;
    wcnt[tid]=c;
  }
  __syncthreads();
  if(tid==0){
    uint runv=0;
    for(int i=0;i<32;i++){ uint c=wcnt[i]; wcnt[i]=runv; runv+=c; }
  }
  __syncthreads();
  if(tid<32){
    u64 m=0; int base=tid*64;
    if(base<n){
      uint rank = wcnt[tid];
      int end = base+64; if(end>n) end=n;
      for(int t2=base;t2<end;t2++){
        uint u = fkey(row[t2]);
        if(u>thr) m |= (1ull<<(t2-base));
        else if(u==thr){ if(rank<k) m |= (1ull<<(t2-base)); rank++; }
      }
    }
    bits[(size_t)s*32+tid]=m;
  }
}

// ---------------- flash attention: no-max exp2 softmax, MFMA row-sum (P x ones), 3 blocks/CU ----------------
__global__ __launch_bounds__(256,3) void flash_attn(
    const u16* __restrict__ q, const u16* __restrict__ k, const u16* __restrict__ vt,
    const u64* __restrict__ bits, u16* __restrict__ o,
    u16* __restrict__ Opart, float* __restrict__ ml)
{
  __shared__ u16 Ks[64*192];
  __shared__ u16 Vt[128*64];
  __shared__ u16 Pl[64*72];
  int h = blockIdx.y;
  int pp = blockIdx.x;
  int sblk=0, chunk=0;
  for(int i=0;i<32;i++){
    int sb = 31-i; int ncc = (sb>>3)+1;
    if(pp < ncc){ sblk=sb; chunk=pp; break; }
    pp -= ncc;
  }
  int nc = (sblk>>3)+1, ntiles = sblk+1, s0 = sblk*64;
  int tid=threadIdx.x, w=tid>>6, l=tid&63;
  int l15=l&15, l16=l>>4;
  // constant all-ones bf16 B-fragment: l = P x 1 via MFMA (all C columns identical)
  u16x8 ones_u;
  #pragma unroll
  for(int j=0;j<8;j++) ones_u[j] = 0x3F80;   // bf16 1.0
  bf16x8 ones = *reinterpret_cast<bf16x8*>(&ones_u);
  bf16x8 qf[6];
  #pragma unroll
  for(int ks=0;ks<6;ks++)
    qf[ks] = *reinterpret_cast<const bf16x8*>(&q[((size_t)(s0+w*16+l15)*16 + h)*192 + ks*32 + l16*8]);
  f32x4 Oa[8];
  #pragma unroll
  for(int n=0;n<8;n++) Oa[n] = f32x4{0.f,0.f,0.f,0.f};
  f32x4 Ol = f32x4{0.f,0.f,0.f,0.f};   // row-sum accumulator (denominator)
  int tt0 = chunk*8, tt1 = imin(tt0+8, ntiles);
  for(int tt=tt0; tt<tt1; tt++){
    int t0 = tt*64;
    __syncthreads();
    #pragma unroll
    for(int rnd=0;rnd<6;rnd++){
      int cid = rnd*256 + w*64 + l;
      int row = cid/24, cc = cid - row*24;
      int scc = cc ^ (row&7);
      GLDS(k + ((size_t)(t0+row)*16 + h)*192 + scc*8, Ks + rnd*2048 + w*512);
    }
    #pragma unroll
    for(int rnd=0;rnd<4;rnd++){
      int cid = rnd*256 + w*64 + l;
      int row = cid>>3, cc = cid&7;
      int scc = cc ^ (row&7);
      GLDS(vt + ((size_t)h*128 + row)*2048 + t0 + scc*8, Vt + rnd*2048 + w*512);
    }
    asm volatile("s_waitcnt vmcnt(0)" ::: "memory");
    __syncthreads();
    f32x4 S[4];
    #pragma unroll
    for(int n=0;n<4;n++) S[n] = f32x4{0.f,0.f,0.f,0.f};
    #pragma unroll
    for(int ks=0;ks<6;ks++){
      bf16x8 b[4];
      #pragma unroll
      for(int n=0;n<4;n++){
        int row = n*16+l15;
        b[n] = *reinterpret_cast<const bf16x8*>(&Ks[row*192 + ((((ks<<2)+l16) ^ (row&7))<<3)]);
      }
      #pragma unroll
      for(int n=0;n<4;n++) S[n] = MFMA(qf[ks], b[n], S[n]);
    }
    bool diag = (tt == sblk);
    #pragma unroll
    for(int r=0;r<4;r++){
      int srow = s0 + w*16 + l16*4 + r;
      u64 wrd = bits[(size_t)srow*32 + (t0>>6)];
      if(diag) wrd &= (((1ull<<(srow&63))<<1) - 1ull);
      #pragma unroll
      for(int n=0;n<4;n++){
        int bitp = n*16 + l15;
        bool ok = (wrd>>bitp)&1ull;
        S[n][r] = ok ? exp2f(S[n][r]) : 0.f;
      }
    }
    #pragma unroll
    for(int n=0;n<4;n++)
      #pragma unroll
      for(int r=0;r<4;r++)
        Pl[(w*16+l16*4+r)*72 + n*16+l15] = f2bf(S[n][r]);
    #pragma unroll
    for(int ks=0;ks<2;ks++){
      bf16x8 a = *reinterpret_cast<const bf16x8*>(&Pl[(w*16+l15)*72 + ks*32 + l16*8]);
      bf16x8 bb[8];
      #pragma unroll
      for(int n=0;n<8;n++){
        int d = n*16+l15;
        bb[n] = *reinterpret_cast<const bf16x8*>(&Vt[d*64 + ((((ks<<2)+l16) ^ (d&7))<<3)]);
      }
      #pragma unroll
      for(int n=0;n<8;n++) Oa[n] = MFMA(a, bb[n], Oa[n]);
      Ol = MFMA(a, ones, Ol);           // denominator: every lane gets row-sum for its rows
    }
  }
  if(nc == 1){
    #pragma unroll
    for(int r=0;r<4;r++){
      int srow = s0 + w*16 + l16*4 + r;
      float inv = 1.f/Ol[r];
      #pragma unroll
      for(int n=0;n<8;n++)
        o[(size_t)srow*2048 + h*128 + n*16 + l15] = f2bf(Oa[n][r]*inv);
    }
  } else {
    int part = ((h*32 + sblk)<<2) + chunk;
    u16* Op = Opart + (size_t)part*8192;
    #pragma unroll
    for(int r=0;r<4;r++){
      int rit = w*16 + l16*4 + r;
      #pragma unroll
      for(int n=0;n<8;n++)
        Op[rit*128 + n*16 + l15] = f2bf(Oa[n][r]);
      if(l15==0)
        ml[(size_t)part*128 + rit*2+1] = Ol[r];
    }
  }
}

__global__ __launch_bounds__(256) void flash_combine(
    const u16* __restrict__ Opart, const float* __restrict__ ml, u16* __restrict__ o)
{
  int b = blockIdx.x;
  int h = b/24, sblk = 8 + (b%24);
  int nc = (sblk>>3)+1;
  int tid = threadIdx.x;
  int r = tid>>2, dq = (tid&3)*32;
  int s0 = sblk*64;
  int pbase = (h*32+sblk)<<2;
  float L = 0.f;
  for(int c=0;c<nc;c++) L += ml[(size_t)(pbase+c)*128 + r*2 + 1];
  float inv = 1.f/L;
  for(int dd=0; dd<32; dd+=8){
    float accv[8];
    #pragma unroll
    for(int j=0;j<8;j++) accv[j]=0.f;
    for(int c=0;c<nc;c++){
      u16x8 pv = *reinterpret_cast<const u16x8*>(&Opart[(size_t)(pbase+c)*8192 + r*128 + dq + dd]);
      #pragma unroll
      for(int j=0;j<8;j++) accv[j] += bf2f(pv[j]);
    }
    u16x8 ov;
    #pragma unroll
    for(int j=0;j<8;j++) ov[j] = f2bf(accv[j]*inv);
    *reinterpret_cast<u16x8*>(&o[(size_t)(s0+r)*2048 + h*128 + dq + dd]) = ov;
  }
}

// ---------------- host ----------------
extern "C" void kernel_launch(void* const* d_in, const int* in_sizes, int n_in,
                              void* d_out, int out_size, void* d_ws, size_t ws_size,
                              hipStream_t stream)
{
  (void)in_sizes; (void)n_in; (void)out_size;
  const float* hs   = (const float*)d_in[0];
  const float* wqa  = (const float*)d_in[1];
  const float* qnw  = (const float*)d_in[2];
  const float* wqbw = (const float*)d_in[3];
  const float* wkva = (const float*)d_in[4];
  const float* kvnw = (const float*)d_in[5];
  const float* wkvb = (const float*)d_in[6];
  const float* wow  = (const float*)d_in[7];
  const float* iwqb = (const float*)d_in[8];
  const float* iwk  = (const float*)d_in[9];
  const float* iknw = (const float*)d_in[10];
  const float* iknb = (const float*)d_in[11];
  const float* iwp  = (const float*)d_in[12];
  const float* fcos = (const float*)d_in[13];
  const float* fsin = (const float*)d_in[14];
  float* outp = (float*)d_out;

  char* base = (char*)d_ws;
  size_t off = 0;
  auto alloc = [&](size_t bytes)->char*{ char* p = base+off; off += (bytes+255)&~(size_t)255; return p; };
  u16* hid_hi = (u16*)alloc(2048ull*2048*2);
  u16* hid_lo = (u16*)alloc(2048ull*2048*2);
  u16* wqa_hi = (u16*)alloc(1536ull*2048*2);
  u16* wqa_lo = (u16*)alloc(1536ull*2048*2);
  u16* wqb_b  = (u16*)alloc(3072ull*1536*2);
  u16* wkva_b = (u16*)alloc(576ull*2048*2);
  u16* wkvb_b = (u16*)alloc(4096ull*512*2);
  u16* wo_b   = (u16*)alloc(2048ull*2048*2);
  u16* iwqb_hi= (u16*)alloc(4096ull*1536*2);
  u16* iwqb_lo= (u16*)alloc(4096ull*1536*2);
  u16* kiwp_hi= (u16*)alloc(160ull*2048*2);
  u16* kiwp_lo= (u16*)alloc(160ull*2048*2);
  float* kiwp_C=(float*)alloc(2048ull*160*4);
  u16* qr_hi  = (u16*)alloc(2048ull*1536*2);
  u16* qr_lo  = (u16*)alloc(2048ull*1536*2);
  u16* kv_b   = (u16*)alloc(2048ull*512*2);
  float* kpe  = (float*)alloc(2048ull*64*4);
  u16* k_b    = (u16*)alloc(2048ull*16*192*2);
  u16* v_t    = (u16*)alloc(16ull*128*2048*2);
  u16* ki_hi  = (u16*)alloc(2048ull*128*2);
  u16* ki_lo  = (u16*)alloc(2048ull*128*2);
  u64* bits   = (u64*)alloc(2048ull*32*8);
  u16* attn_b = (u16*)alloc(2048ull*2048*2);
  float* reg1 = (float*)alloc(2048ull*4096*4);
  if(ws_size < off) return;

  // aliases (lifetime-checked)
  u16* q_b      = wqa_hi;            // spans wqa_hi+wqa_lo; wq_a dead after qr gemm; written by q-GEMM EPI=1
  u16* qi_hi    = hid_hi;            // spans hid_hi+hid_lo; hidden dead after kiwp gemm
  u16* qi_lo    = iwqb_hi;           // spans into iwqb_lo; idx_wq_b dead after qi gemm
  float* ml     = (float*)qr_lo;     // qr dead after qi gemm
  float* qr_pre = reg1;
  float* kva_part = reg1;
  float* kvp    = reg1;
  float* kiwp_part = reg1;
  float* qi_pre = reg1;
  const size_t PLANE = 272ull*8192;
  float* ip0 = reg1;
  float* ip1 = reg1 + PLANE;
  float* ip2 = reg1 + 2*PLANE;
  float* ip3 = (float*)wqb_b;        // wqb_b dead after q gemm
  u16* Opart = (u16*)reg1;

  auto G1 = [&](const u16* A,int lda,const u16* B,int ldb,float* C,int ldc,int M,int N,int K,int z){
    dim3 g((unsigned)((N+127)/128), (unsigned)((M+127)/128), (unsigned)z);
    gemm_glds<0,64,0><<<g,256,0,stream>>>(A,nullptr,lda,B,nullptr,ldb,C,ldc,M,N,K,nullptr,nullptr,nullptr);
  };
  auto G3 = [&](const u16* Ah,const u16* Al,int lda,const u16* Bh,const u16* Bl,int ldb,float* C,int ldc,int M,int N,int K,int z){
    dim3 g((unsigned)((N+127)/128), (unsigned)((M+127)/128), (unsigned)z);
    gemm_glds<1,64,0><<<g,256,0,stream>>>(Ah,Al,lda,Bh,Bl,ldb,C,ldc,M,N,K,nullptr,nullptr,nullptr);
  };

  cvt_all<<<2048,256,0,stream>>>(hs,wqa,iwqb,iwk,iwp,wqbw,wkva,wkvb,wow,
      hid_hi,hid_lo,wqa_hi,wqa_lo,iwqb_hi,iwqb_lo,kiwp_hi,kiwp_lo,
      wqb_b,wkva_b,wkvb_b,wo_b);

  // qr = rmsnorm(hidden @ wq_a^T), split-K z=2, plane-sum fused into rmsnorm
  G3(hid_hi,hid_lo,2048, wqa_hi,wqa_lo,2048, qr_pre,1536, 2048,1536,2048, 2);
  rmsnorm_qr_split<<<2048,256,0,stream>>>(qr_pre, qnw, qr_hi, qr_lo);

  // q path: GEMM with fused rope+scale+bf16 epilogue (writes q_b directly)
  {
    dim3 g(24, 16, 1);
    gemm_glds<0,64,1><<<g,256,0,stream>>>(qr_hi,nullptr,1536, wqb_b,nullptr,1536,
        nullptr,0, 2048,3072,1536, q_b, fcos, fsin);
  }

  // kv path (split-K z=4, plane-sum fused into kv_norm_rope)
  G1(hid_hi,2048, wkva_b,2048, kva_part,576, 2048,576,2048, 4);
  kv_norm_rope<<<2048,256,0,stream>>>(kva_part, kvnw, fcos, fsin, kv_b, kpe);
  G1(kv_b,512, wkvb_b,512, kvp,4096, 2048,4096,512, 1);
  transpose_assemble<<<dim3(32,16),256,0,stream>>>(kvp, kpe, v_t, k_b);

  // indexer ki + wts packed (N=160, split-K z=8)
  G3(hid_hi,hid_lo,2048, kiwp_hi,kiwp_lo,2048, kiwp_part,160, 2048,160,2048, 8);
  ki_ln_rope_split<<<2048,128,0,stream>>>(kiwp_part, iknw, iknb, fcos, fsin, ki_hi, ki_lo, kiwp_C);

  // indexer qi
  G3(qr_hi,qr_lo,1536, iwqb_hi,iwqb_lo,1536, qi_pre,4096, 2048,4096,1536, 1);
  qi_rope_split<<<2048,256,0,stream>>>(qi_pre, fcos, fsin, qi_hi, qi_lo);

  // fused index scores + topk
  idx_scores7<<<1088,512,0,stream>>>(qi_hi, qi_lo, ki_hi, ki_lo, kiwp_C, ip0, ip1, ip2, ip3);
  topk_mask<<<2048,256,0,stream>>>(ip0, ip1, ip2, ip3, bits);

  // attention + combine + output projection
  flash_attn<<<dim3(80,16),256,0,stream>>>(q_b, k_b, v_t, bits, attn_b, Opart, ml);
  flash_combine<<<384,256,0,stream>>>(Opart, ml, attn_b);
  G1(attn_b,2048, wo_b,2048, outp,2048, 2048,2048,2048, 1);
}